// Round 1
// baseline (385.280 us; speedup 1.0000x reference)
//
#include <hip/hip_runtime.h>

typedef float  f32x4  __attribute__((ext_vector_type(4)));
typedef __bf16 bf16x8 __attribute__((ext_vector_type(8)));
typedef short  short8 __attribute__((ext_vector_type(8)));
typedef short  short4v __attribute__((ext_vector_type(4)));

#define MFMA(a,b,c) __builtin_amdgcn_mfma_f32_16x16x32_bf16(a,b,c,0,0,0)

__device__ __forceinline__ short f2bf(float x){
  unsigned u = __builtin_bit_cast(unsigned, x);
  u = (u + 0x7fffu + ((u >> 16) & 1u)) >> 16;   // RNE
  return (short)u;
}
__device__ __forceinline__ float bf2f(short s){
  return __builtin_bit_cast(float, ((unsigned)(unsigned short)s) << 16);
}

#define S_LEN 2048
#define E_DIM 1024
#define H_NUM 16
#define D_DIM 64
#define NBH   32
#define M_ROWS 4096
#define N3    3072

// ---------------- prep: fp32 -> (hi,lo) bf16 split ----------------
__global__ void split_x_kernel(const float* __restrict__ in,
                               short* __restrict__ hi, short* __restrict__ lo, int n4){
  int i = blockIdx.x * 256 + threadIdx.x;
  if (i >= n4) return;
  const float4 v = reinterpret_cast<const float4*>(in)[i];
  float xs[4] = {v.x, v.y, v.z, v.w};
  short4v h, l;
#pragma unroll
  for (int j = 0; j < 4; ++j){
    short hh = f2bf(xs[j]);
    h[j] = hh;
    l[j] = f2bf(xs[j] - bf2f(hh));
  }
  reinterpret_cast<short4v*>(hi)[i] = h;
  reinterpret_cast<short4v*>(lo)[i] = l;
}

// out[n][k] = in[k][n], split into hi/lo. in is R x C, out is C x R.
__global__ void transpose_split(const float* __restrict__ in,
                                short* __restrict__ hi, short* __restrict__ lo,
                                int R, int C){
  __shared__ float tile[32][33];
  int bx = blockIdx.x * 32, by = blockIdx.y * 32;
  int tx = threadIdx.x & 31, ty = threadIdx.x >> 5;   // 256 threads = 32x8
#pragma unroll
  for (int i = ty; i < 32; i += 8)
    tile[i][tx] = in[(size_t)(by + i) * C + bx + tx];
  __syncthreads();
#pragma unroll
  for (int i = ty; i < 32; i += 8){
    float v = tile[tx][i];
    size_t o = (size_t)(bx + i) * R + by + tx;
    short h = f2bf(v);
    hi[o] = h;
    lo[o] = f2bf(v - bf2f(h));
  }
}

// ---------------- split-bf16 GEMM: C = A @ B^T(rowmajor N x K) ----------------
// A: M x K (hi/lo), B: N x K (hi/lo).  3-term: Ah*Bh + Ah*Bl + Al*Bh.
// EPI=0: write fp32 C (M x Ndim).  EPI=1: scatter qkv -> Q(+0.125 scale)/K/V hi/lo (B,H,S,D).
template<int EPI>
__global__ __launch_bounds__(256, 2) void gemm3(
    const short* __restrict__ Ah, const short* __restrict__ Al,
    const short* __restrict__ Bh, const short* __restrict__ Bl,
    int Kdim, int Ndim, float* __restrict__ Cout,
    short* __restrict__ qh, short* __restrict__ ql,
    short* __restrict__ kh, short* __restrict__ kl,
    short* __restrict__ vh, short* __restrict__ vl)
{
  constexpr int LDT = 72;   // 64 + 8 pad: 144B rows -> 2-way bank aliasing (free), 16B aligned
  __shared__ __align__(16) short sAh[128][LDT], sAl[128][LDT], sBh[128][LDT], sBl[128][LDT];
  const int tid = threadIdx.x;
  const int m0 = blockIdx.y * 128, n0 = blockIdx.x * 128;
  const int wid = tid >> 6, lane = tid & 63;
  const int wr = (wid >> 1) * 64, wc = (wid & 1) * 64;
  const int lr = lane & 15, lc = lane >> 4;

  f32x4 acc[4][4] = {};
  const int nK = Kdim >> 6;
  for (int ks = 0; ks < nK; ++ks){
    const int k0 = ks << 6;
#pragma unroll
    for (int p = 0; p < 4; ++p){
      const int i = tid + p * 256;             // 1024 16B chunks per tile
      const int r = i >> 3, c8 = (i & 7) * 8;
      const size_t ga = (size_t)(m0 + r) * Kdim + k0 + c8;
      const size_t gb = (size_t)(n0 + r) * Kdim + k0 + c8;
      *reinterpret_cast<int4*>(&sAh[r][c8]) = *reinterpret_cast<const int4*>(&Ah[ga]);
      *reinterpret_cast<int4*>(&sAl[r][c8]) = *reinterpret_cast<const int4*>(&Al[ga]);
      *reinterpret_cast<int4*>(&sBh[r][c8]) = *reinterpret_cast<const int4*>(&Bh[gb]);
      *reinterpret_cast<int4*>(&sBl[r][c8]) = *reinterpret_cast<const int4*>(&Bl[gb]);
    }
    __syncthreads();
#pragma unroll
    for (int kk = 0; kk < 64; kk += 32){
      bf16x8 fah[4], fal[4], fbh[4], fbl[4];
#pragma unroll
      for (int t = 0; t < 4; ++t){
        fah[t] = *reinterpret_cast<const bf16x8*>(&sAh[wr + t*16 + lr][kk + lc*8]);
        fal[t] = *reinterpret_cast<const bf16x8*>(&sAl[wr + t*16 + lr][kk + lc*8]);
        fbh[t] = *reinterpret_cast<const bf16x8*>(&sBh[wc + t*16 + lr][kk + lc*8]);
        fbl[t] = *reinterpret_cast<const bf16x8*>(&sBl[wc + t*16 + lr][kk + lc*8]);
      }
#pragma unroll
      for (int mt = 0; mt < 4; ++mt)
#pragma unroll
        for (int nt = 0; nt < 4; ++nt){
          f32x4 c = acc[mt][nt];
          c = MFMA(fah[mt], fbh[nt], c);
          c = MFMA(fah[mt], fbl[nt], c);
          c = MFMA(fal[mt], fbh[nt], c);
          acc[mt][nt] = c;
        }
    }
    __syncthreads();
  }
  // epilogue: C/D layout col=lane&15, row=(lane>>4)*4+reg  [m89]
#pragma unroll
  for (int mt = 0; mt < 4; ++mt)
#pragma unroll
    for (int nt = 0; nt < 4; ++nt)
#pragma unroll
      for (int r = 0; r < 4; ++r){
        const int m = m0 + wr + mt*16 + lc*4 + r;
        const int n = n0 + wc + nt*16 + lr;
        float v = acc[mt][nt][r];
        if (EPI == 0){
          Cout[(size_t)m * Ndim + n] = v;
        } else {
          const int t = n >> 10, rem = n & 1023, hh = rem >> 6, d = rem & 63;
          const int b = m >> 11, s = m & 2047;
          if (t == 0) v *= 0.125f;            // fold 1/sqrt(64) into Q
          const size_t o = ((size_t)(b*H_NUM + hh) * S_LEN + s) * D_DIM + d;
          short* ph = (t == 0) ? qh : (t == 1) ? kh : vh;
          short* pl = (t == 0) ? ql : (t == 1) ? kl : vl;
          const short hv = f2bf(v);
          ph[o] = hv;
          pl[o] = f2bf(v - bf2f(hv));
        }
      }
}

// ---------------- flash attention with ghost softmax ----------------
// WG: (qb, bh). 4 waves x 16 q-rows = 64 q-rows. KV blocks of 64, causal.
__global__ __launch_bounds__(256, 2) void attn_kernel(
    const short* __restrict__ Qh, const short* __restrict__ Ql,
    const short* __restrict__ Kh, const short* __restrict__ Kl,
    const short* __restrict__ Vh, const short* __restrict__ Vl,
    short* __restrict__ Aoh, short* __restrict__ Aol)
{
  constexpr int LDV = 72;
  __shared__ __align__(16) short sVh[64][LDV], sVl[64][LDV];   // V^T: [d][token]
  __shared__ __align__(16) short sP[4][16][LDV];               // per-wave P tile [q][token]
  const int tid = threadIdx.x, wid = tid >> 6, lane = tid & 63;
  const int qb = blockIdx.x, bh = blockIdx.y;
  const int q0 = qb * 64;
  const int lr = lane & 15, lc = lane >> 4;
  const size_t base = (size_t)bh * S_LEN * D_DIM;

  // Q fragments (A-operand), hoisted; Q already scaled by 1/8
  bf16x8 fqh[2], fql[2];
  {
    const int qrow = q0 + wid*16 + lr;
#pragma unroll
    for (int kc = 0; kc < 2; ++kc){
      const size_t o = base + (size_t)qrow * 64 + kc*32 + lc*8;
      fqh[kc] = *reinterpret_cast<const bf16x8*>(&Qh[o]);
      fql[kc] = *reinterpret_cast<const bf16x8*>(&Ql[o]);
    }
  }

  f32x4 acc[4] = {};
  float mrow[4], lrow[4];
#pragma unroll
  for (int r = 0; r < 4; ++r){ mrow[r] = -1e30f; lrow[r] = 0.f; }

  for (int t = 0; t <= qb; ++t){
    const int kv0 = t * 64;
    // stage V^T hi/lo into LDS (transposed scatter-write; 2-way aliasing only)
#pragma unroll
    for (int p = 0; p < 2; ++p){
      const int i = tid + p*256;
      const int tok = i >> 3, c8 = (i & 7) * 8;
      const size_t o = base + (size_t)(kv0 + tok) * 64 + c8;
      const short8 vhv = *reinterpret_cast<const short8*>(&Vh[o]);
      const short8 vlv = *reinterpret_cast<const short8*>(&Vl[o]);
#pragma unroll
      for (int j = 0; j < 8; ++j){
        sVh[c8 + j][tok] = vhv[j];
        sVl[c8 + j][tok] = vlv[j];
      }
    }
    __syncthreads();

    // scores: 3-term split QK^T; K frags read straight from global (L2-resident)
    f32x4 sc[4];
#pragma unroll
    for (int nt = 0; nt < 4; ++nt){
      f32x4 z = {};
      const int ktok = kv0 + nt*16 + lr;
#pragma unroll
      for (int kc = 0; kc < 2; ++kc){
        const size_t o = base + (size_t)ktok * 64 + kc*32 + lc*8;
        const bf16x8 fkh = *reinterpret_cast<const bf16x8*>(&Kh[o]);
        const bf16x8 fkl = *reinterpret_cast<const bf16x8*>(&Kl[o]);
        z = MFMA(fqh[kc], fkh, z);
        z = MFMA(fqh[kc], fkl, z);
        z = MFMA(fql[kc], fkh, z);
      }
      sc[nt] = z;
    }

    if (t == qb){   // diagonal block: mask k > q
#pragma unroll
      for (int nt = 0; nt < 4; ++nt)
#pragma unroll
        for (int r = 0; r < 4; ++r)
          if (nt*16 + lr > wid*16 + lc*4 + r) sc[nt][r] = -1e30f;
    }

    // online softmax over this block (rows live in lanes with same lane>>4)
#pragma unroll
    for (int r = 0; r < 4; ++r){
      float mx = fmaxf(fmaxf(sc[0][r], sc[1][r]), fmaxf(sc[2][r], sc[3][r]));
#pragma unroll
      for (int off = 1; off < 16; off <<= 1)
        mx = fmaxf(mx, __shfl_xor(mx, off));
      const float mn = fmaxf(mrow[r], mx);
      const float scale = __expf(mrow[r] - mn);
      float sum = 0.f;
#pragma unroll
      for (int nt = 0; nt < 4; ++nt){
        const float pv = __expf(sc[nt][r] - mn);
        sc[nt][r] = pv;
        sum += pv;
      }
#pragma unroll
      for (int off = 1; off < 16; off <<= 1)
        sum += __shfl_xor(sum, off);
      lrow[r] = lrow[r] * scale + sum;
      mrow[r] = mn;
#pragma unroll
      for (int dt = 0; dt < 4; ++dt) acc[dt][r] *= scale;
    }

    // P (bf16) -> per-wave LDS tile, then read back in A-frag layout
#pragma unroll
    for (int nt = 0; nt < 4; ++nt)
#pragma unroll
      for (int r = 0; r < 4; ++r)
        sP[wid][lc*4 + r][nt*16 + lr] = f2bf(sc[nt][r]);

    bf16x8 pa[2];
#pragma unroll
    for (int kc = 0; kc < 2; ++kc)
      pa[kc] = *reinterpret_cast<const bf16x8*>(&sP[wid][lr][kc*32 + lc*8]);
#pragma unroll
    for (int dt = 0; dt < 4; ++dt){
#pragma unroll
      for (int kc = 0; kc < 2; ++kc){
        const bf16x8 fvh = *reinterpret_cast<const bf16x8*>(&sVh[dt*16 + lr][kc*32 + lc*8]);
        const bf16x8 fvl = *reinterpret_cast<const bf16x8*>(&sVl[dt*16 + lr][kc*32 + lc*8]);
        acc[dt] = MFMA(pa[kc], fvh, acc[dt]);
        acc[dt] = MFMA(pa[kc], fvl, acc[dt]);
      }
    }
    __syncthreads();
  }

  // finalize: ghost softmax divides by (l + 1); write A hi/lo in (B,S,H*D)
  const int b = bh >> 4, hh = bh & 15;
#pragma unroll
  for (int dt = 0; dt < 4; ++dt)
#pragma unroll
    for (int r = 0; r < 4; ++r){
      const float o = acc[dt][r] / (lrow[r] + 1.0f);
      const int q = q0 + wid*16 + lc*4 + r;
      const int d = dt*16 + lr;
      const size_t off = ((size_t)(b*S_LEN + q)) * E_DIM + hh*D_DIM + d;
      const short hv = f2bf(o);
      Aoh[off] = hv;
      Aol[off] = f2bf(o - bf2f(hv));
    }
}

// ---------------- launch ----------------
extern "C" void kernel_launch(void* const* d_in, const int* in_sizes, int n_in,
                              void* d_out, int out_size, void* d_ws, size_t ws_size,
                              hipStream_t stream){
  const float* X    = (const float*)d_in[0];
  const float* Wqkv = (const float*)d_in[1];
  const float* Wo   = (const float*)d_in[2];
  float* out = (float*)d_out;

  short* w = (short*)d_ws;
  size_t off = 0;
  auto alloc = [&](size_t n){ short* p = w + off; off += n; return p; };
  const size_t ME   = (size_t)M_ROWS * E_DIM;   // 4.19M
  const size_t WQ   = (size_t)N3 * E_DIM;       // 3.15M
  const size_t WOsz = (size_t)E_DIM * E_DIM;    // 1.05M
  const size_t QK   = (size_t)NBH * S_LEN * D_DIM; // 4.19M
  short *Xhi = alloc(ME), *Xlo = alloc(ME);
  short *Wqh = alloc(WQ), *Wql = alloc(WQ);
  short *Woh = alloc(WOsz), *Wol = alloc(WOsz);
  short *Qh = alloc(QK), *Ql_ = alloc(QK);
  short *Kh = alloc(QK), *Kl  = alloc(QK);
  short *Vh = alloc(QK), *Vl  = alloc(QK);
  short *Ahh = alloc(ME), *Ahl = alloc(ME);
  // total ~50.4M shorts ~ 101 MB of d_ws

  split_x_kernel<<<(int)(ME/4/256), 256, 0, stream>>>(X, Xhi, Xlo, (int)(ME/4));
  transpose_split<<<dim3(N3/32, E_DIM/32), 256, 0, stream>>>(Wqkv, Wqh, Wql, E_DIM, N3);
  transpose_split<<<dim3(E_DIM/32, E_DIM/32), 256, 0, stream>>>(Wo, Woh, Wol, E_DIM, E_DIM);

  gemm3<1><<<dim3(N3/128, M_ROWS/128), 256, 0, stream>>>(
      Xhi, Xlo, Wqh, Wql, E_DIM, N3, nullptr, Qh, Ql_, Kh, Kl, Vh, Vl);

  attn_kernel<<<dim3(S_LEN/64, NBH), 256, 0, stream>>>(
      Qh, Ql_, Kh, Kl, Vh, Vl, Ahh, Ahl);

  gemm3<0><<<dim3(E_DIM/128, M_ROWS/128), 256, 0, stream>>>(
      Ahh, Ahl, Woh, Wol, E_DIM, E_DIM, out,
      nullptr, nullptr, nullptr, nullptr, nullptr, nullptr);
}

// Round 2
// 343.309 us; speedup vs baseline: 1.1223x; 1.1223x over previous
//
#include <hip/hip_runtime.h>

typedef float  f32x4  __attribute__((ext_vector_type(4)));
typedef __bf16 bf16x8 __attribute__((ext_vector_type(8)));
typedef short  short8 __attribute__((ext_vector_type(8)));
typedef short  short4v __attribute__((ext_vector_type(4)));

#define MFMA(a,b,c) __builtin_amdgcn_mfma_f32_16x16x32_bf16(a,b,c,0,0,0)

__device__ __forceinline__ short f2bf(float x){
  unsigned u = __builtin_bit_cast(unsigned, x);
  u = (u + 0x7fffu + ((u >> 16) & 1u)) >> 16;   // RNE
  return (short)u;
}
__device__ __forceinline__ float bf2f(short s){
  return __builtin_bit_cast(float, ((unsigned)(unsigned short)s) << 16);
}

#define S_LEN 2048
#define E_DIM 1024
#define H_NUM 16
#define D_DIM 64
#define NBH   32
#define M_ROWS 4096
#define N3    3072

// ---------------- prep: fp32 -> (hi,lo) bf16 split ----------------
__global__ void split_x_kernel(const float* __restrict__ in,
                               short* __restrict__ hi, short* __restrict__ lo, int n4){
  int i = blockIdx.x * 256 + threadIdx.x;
  if (i >= n4) return;
  const float4 v = reinterpret_cast<const float4*>(in)[i];
  float xs[4] = {v.x, v.y, v.z, v.w};
  short4v h, l;
#pragma unroll
  for (int j = 0; j < 4; ++j){
    short hh = f2bf(xs[j]);
    h[j] = hh;
    l[j] = f2bf(xs[j] - bf2f(hh));
  }
  reinterpret_cast<short4v*>(hi)[i] = h;
  reinterpret_cast<short4v*>(lo)[i] = l;
}

// out[n][k] = in[k][n], split into hi/lo. in is R x C, out is C x R.
__global__ void transpose_split(const float* __restrict__ in,
                                short* __restrict__ hi, short* __restrict__ lo,
                                int R, int C){
  __shared__ float tile[32][33];
  int bx = blockIdx.x * 32, by = blockIdx.y * 32;
  int tx = threadIdx.x & 31, ty = threadIdx.x >> 5;   // 256 threads = 32x8
#pragma unroll
  for (int i = ty; i < 32; i += 8)
    tile[i][tx] = in[(size_t)(by + i) * C + bx + tx];
  __syncthreads();
#pragma unroll
  for (int i = ty; i < 32; i += 8){
    float v = tile[tx][i];
    size_t o = (size_t)(bx + i) * R + by + tx;
    short h = f2bf(v);
    hi[o] = h;
    lo[o] = f2bf(v - bf2f(h));
  }
}

// ---------------- split-bf16 GEMM: C = A @ B^T(rowmajor N x K) ----------------
// A: M x K (hi/lo), B: N x K (hi/lo).  3-term: Ah*Bh + Ah*Bl + Al*Bh.
// EPI=0: write fp32 C (M x Ndim).
// EPI=1: scatter qkv -> Q(+0.125 scale)[bh][s][d], K[bh][s][d], V^T[bh][d][s] hi/lo.
template<int EPI>
__global__ __launch_bounds__(256, 2) void gemm3(
    const short* __restrict__ Ah, const short* __restrict__ Al,
    const short* __restrict__ Bh, const short* __restrict__ Bl,
    int Kdim, int Ndim, float* __restrict__ Cout,
    short* __restrict__ qh, short* __restrict__ ql,
    short* __restrict__ kh, short* __restrict__ kl,
    short* __restrict__ vh, short* __restrict__ vl)
{
  constexpr int LDT = 72;   // 64 + 8 pad
  __shared__ __align__(16) short sAh[128][LDT], sAl[128][LDT], sBh[128][LDT], sBl[128][LDT];
  const int tid = threadIdx.x;
  const int m0 = blockIdx.y * 128, n0 = blockIdx.x * 128;
  const int wid = tid >> 6, lane = tid & 63;
  const int wr = (wid >> 1) * 64, wc = (wid & 1) * 64;
  const int lr = lane & 15, lc = lane >> 4;

  f32x4 acc[4][4] = {};
  const int nK = Kdim >> 6;
  for (int ks = 0; ks < nK; ++ks){
    const int k0 = ks << 6;
#pragma unroll
    for (int p = 0; p < 4; ++p){
      const int i = tid + p * 256;             // 1024 16B chunks per tile
      const int r = i >> 3, c8 = (i & 7) * 8;
      const size_t ga = (size_t)(m0 + r) * Kdim + k0 + c8;
      const size_t gb = (size_t)(n0 + r) * Kdim + k0 + c8;
      *reinterpret_cast<int4*>(&sAh[r][c8]) = *reinterpret_cast<const int4*>(&Ah[ga]);
      *reinterpret_cast<int4*>(&sAl[r][c8]) = *reinterpret_cast<const int4*>(&Al[ga]);
      *reinterpret_cast<int4*>(&sBh[r][c8]) = *reinterpret_cast<const int4*>(&Bh[gb]);
      *reinterpret_cast<int4*>(&sBl[r][c8]) = *reinterpret_cast<const int4*>(&Bl[gb]);
    }
    __syncthreads();
#pragma unroll
    for (int kk = 0; kk < 64; kk += 32){
      bf16x8 fah[4], fal[4], fbh[4], fbl[4];
#pragma unroll
      for (int t = 0; t < 4; ++t){
        fah[t] = *reinterpret_cast<const bf16x8*>(&sAh[wr + t*16 + lr][kk + lc*8]);
        fal[t] = *reinterpret_cast<const bf16x8*>(&sAl[wr + t*16 + lr][kk + lc*8]);
        fbh[t] = *reinterpret_cast<const bf16x8*>(&sBh[wc + t*16 + lr][kk + lc*8]);
        fbl[t] = *reinterpret_cast<const bf16x8*>(&sBl[wc + t*16 + lr][kk + lc*8]);
      }
#pragma unroll
      for (int mt = 0; mt < 4; ++mt)
#pragma unroll
        for (int nt = 0; nt < 4; ++nt){
          f32x4 c = acc[mt][nt];
          c = MFMA(fah[mt], fbh[nt], c);
          c = MFMA(fah[mt], fbl[nt], c);
          c = MFMA(fal[mt], fbh[nt], c);
          acc[mt][nt] = c;
        }
    }
    __syncthreads();
  }
  // epilogue: C/D layout col=lane&15, row=(lane>>4)*4+reg  [m89]
#pragma unroll
  for (int mt = 0; mt < 4; ++mt)
#pragma unroll
    for (int nt = 0; nt < 4; ++nt)
#pragma unroll
      for (int r = 0; r < 4; ++r){
        const int m = m0 + wr + mt*16 + lc*4 + r;
        const int n = n0 + wc + nt*16 + lr;
        float v = acc[mt][nt][r];
        if (EPI == 0){
          Cout[(size_t)m * Ndim + n] = v;
        } else {
          const int t = n >> 10, rem = n & 1023, hh = rem >> 6, d = rem & 63;
          const int b = m >> 11, s = m & 2047;
          const int bh = b * H_NUM + hh;
          if (t == 0) v *= 0.125f;            // fold 1/sqrt(64) into Q
          size_t o;
          if (t == 2)  o = ((size_t)bh * D_DIM + d) * S_LEN + s;   // V transposed
          else         o = ((size_t)bh * S_LEN + s) * D_DIM + d;
          short* ph = (t == 0) ? qh : (t == 1) ? kh : vh;
          short* pl = (t == 0) ? ql : (t == 1) ? kl : vl;
          const short hv = f2bf(v);
          ph[o] = hv;
          pl[o] = f2bf(v - bf2f(hv));
        }
      }
}

// ---------------- flash attention with ghost softmax ----------------
// WG: (qb, bh). 4 waves x 16 q-rows = 64 q-rows. KV blocks of 64, causal.
// K[bh][s][d] and Vt[bh][d][s] both staged in LDS (hi/lo), conflict-free b128.
__global__ __launch_bounds__(256, 2) void attn_kernel(
    const short* __restrict__ Qh, const short* __restrict__ Ql,
    const short* __restrict__ Kh, const short* __restrict__ Kl,
    const short* __restrict__ Vth, const short* __restrict__ Vtl,
    short* __restrict__ Aoh, short* __restrict__ Aol)
{
  constexpr int LDV = 72;
  __shared__ __align__(16) short sKh[64][LDV], sKl[64][LDV];   // K: [token][d]
  __shared__ __align__(16) short sVh[64][LDV], sVl[64][LDV];   // V^T: [d][token]
  __shared__ __align__(16) short sP[4][16][LDV];               // per-wave P tile [q][token]
  const int tid = threadIdx.x, wid = tid >> 6, lane = tid & 63;
  const int qb = (int)gridDim.x - 1 - (int)blockIdx.x;   // heaviest blocks dispatch first
  const int bh = blockIdx.y;
  const int q0 = qb * 64;
  const int lr = lane & 15, lc = lane >> 4;
  const size_t base = (size_t)bh * S_LEN * D_DIM;        // same size for K and Vt

  // Q fragments (A-operand), hoisted; Q already scaled by 1/8
  bf16x8 fqh[2], fql[2];
  {
    const int qrow = q0 + wid*16 + lr;
#pragma unroll
    for (int kc = 0; kc < 2; ++kc){
      const size_t o = base + (size_t)qrow * 64 + kc*32 + lc*8;
      fqh[kc] = *reinterpret_cast<const bf16x8*>(&Qh[o]);
      fql[kc] = *reinterpret_cast<const bf16x8*>(&Ql[o]);
    }
  }

  f32x4 acc[4] = {};
  float mrow[4], lrow[4];
#pragma unroll
  for (int r = 0; r < 4; ++r){ mrow[r] = -1e30f; lrow[r] = 0.f; }

  for (int t = 0; t <= qb; ++t){
    const int kv0 = t * 64;
    // stage K[tok][d] and Vt[d][tok] hi/lo: vectorized, conflict-free
#pragma unroll
    for (int p = 0; p < 2; ++p){
      const int i = tid + p*256;               // 0..511
      const int r = i >> 3, c8 = (i & 7) * 8;
      const size_t oK = base + (size_t)(kv0 + r) * D_DIM + c8;
      const size_t oV = base + (size_t)r * S_LEN + kv0 + c8;
      *reinterpret_cast<int4*>(&sKh[r][c8]) = *reinterpret_cast<const int4*>(&Kh[oK]);
      *reinterpret_cast<int4*>(&sKl[r][c8]) = *reinterpret_cast<const int4*>(&Kl[oK]);
      *reinterpret_cast<int4*>(&sVh[r][c8]) = *reinterpret_cast<const int4*>(&Vth[oV]);
      *reinterpret_cast<int4*>(&sVl[r][c8]) = *reinterpret_cast<const int4*>(&Vtl[oV]);
    }
    __syncthreads();

    // scores: 3-term split QK^T from LDS
    f32x4 sc[4];
#pragma unroll
    for (int nt = 0; nt < 4; ++nt){
      f32x4 z = {};
#pragma unroll
      for (int kc = 0; kc < 2; ++kc){
        const bf16x8 fkh = *reinterpret_cast<const bf16x8*>(&sKh[nt*16 + lr][kc*32 + lc*8]);
        const bf16x8 fkl = *reinterpret_cast<const bf16x8*>(&sKl[nt*16 + lr][kc*32 + lc*8]);
        z = MFMA(fqh[kc], fkh, z);
        z = MFMA(fqh[kc], fkl, z);
        z = MFMA(fql[kc], fkh, z);
      }
      sc[nt] = z;
    }

    if (t == qb){   // diagonal block: mask k > q
#pragma unroll
      for (int nt = 0; nt < 4; ++nt)
#pragma unroll
        for (int r = 0; r < 4; ++r)
          if (nt*16 + lr > wid*16 + lc*4 + r) sc[nt][r] = -1e30f;
    }

    // online softmax over this block (rows live in lanes with same lane>>4)
#pragma unroll
    for (int r = 0; r < 4; ++r){
      float mx = fmaxf(fmaxf(sc[0][r], sc[1][r]), fmaxf(sc[2][r], sc[3][r]));
#pragma unroll
      for (int off = 1; off < 16; off <<= 1)
        mx = fmaxf(mx, __shfl_xor(mx, off));
      const float mn = fmaxf(mrow[r], mx);
      const float scale = __expf(mrow[r] - mn);
      float sum = 0.f;
#pragma unroll
      for (int nt = 0; nt < 4; ++nt){
        const float pv = __expf(sc[nt][r] - mn);
        sc[nt][r] = pv;
        sum += pv;
      }
#pragma unroll
      for (int off = 1; off < 16; off <<= 1)
        sum += __shfl_xor(sum, off);
      lrow[r] = lrow[r] * scale + sum;
      mrow[r] = mn;
#pragma unroll
      for (int dt = 0; dt < 4; ++dt) acc[dt][r] *= scale;
    }

    // P (bf16) -> per-wave LDS tile, then read back in A-frag layout
#pragma unroll
    for (int nt = 0; nt < 4; ++nt)
#pragma unroll
      for (int r = 0; r < 4; ++r)
        sP[wid][lc*4 + r][nt*16 + lr] = f2bf(sc[nt][r]);

    bf16x8 pa[2];
#pragma unroll
    for (int kc = 0; kc < 2; ++kc)
      pa[kc] = *reinterpret_cast<const bf16x8*>(&sP[wid][lr][kc*32 + lc*8]);
#pragma unroll
    for (int dt = 0; dt < 4; ++dt){
#pragma unroll
      for (int kc = 0; kc < 2; ++kc){
        const bf16x8 fvh = *reinterpret_cast<const bf16x8*>(&sVh[dt*16 + lr][kc*32 + lc*8]);
        const bf16x8 fvl = *reinterpret_cast<const bf16x8*>(&sVl[dt*16 + lr][kc*32 + lc*8]);
        acc[dt] = MFMA(pa[kc], fvh, acc[dt]);
        acc[dt] = MFMA(pa[kc], fvl, acc[dt]);
      }
    }
    __syncthreads();
  }

  // finalize: ghost softmax divides by (l + 1); write A hi/lo in (B,S,H*D)
  const int b = bh >> 4, hh = bh & 15;
#pragma unroll
  for (int dt = 0; dt < 4; ++dt)
#pragma unroll
    for (int r = 0; r < 4; ++r){
      const float o = acc[dt][r] / (lrow[r] + 1.0f);
      const int q = q0 + wid*16 + lc*4 + r;
      const int d = dt*16 + lr;
      const size_t off = ((size_t)(b*S_LEN + q)) * E_DIM + hh*D_DIM + d;
      const short hv = f2bf(o);
      Aoh[off] = hv;
      Aol[off] = f2bf(o - bf2f(hv));
    }
}

// ---------------- launch ----------------
extern "C" void kernel_launch(void* const* d_in, const int* in_sizes, int n_in,
                              void* d_out, int out_size, void* d_ws, size_t ws_size,
                              hipStream_t stream){
  const float* X    = (const float*)d_in[0];
  const float* Wqkv = (const float*)d_in[1];
  const float* Wo   = (const float*)d_in[2];
  float* out = (float*)d_out;

  short* w = (short*)d_ws;
  size_t off = 0;
  auto alloc = [&](size_t n){ short* p = w + off; off += n; return p; };
  const size_t ME   = (size_t)M_ROWS * E_DIM;
  const size_t WQ   = (size_t)N3 * E_DIM;
  const size_t WOsz = (size_t)E_DIM * E_DIM;
  const size_t QK   = (size_t)NBH * S_LEN * D_DIM;
  short *Xhi = alloc(ME), *Xlo = alloc(ME);
  short *Wqh = alloc(WQ), *Wql = alloc(WQ);
  short *Woh = alloc(WOsz), *Wol = alloc(WOsz);
  short *Qh = alloc(QK), *Ql_ = alloc(QK);
  short *Kh = alloc(QK), *Kl  = alloc(QK);
  short *Vth = alloc(QK), *Vtl = alloc(QK);
  short *Ahh = alloc(ME), *Ahl = alloc(ME);

  split_x_kernel<<<(int)(ME/4/256), 256, 0, stream>>>(X, Xhi, Xlo, (int)(ME/4));
  transpose_split<<<dim3(N3/32, E_DIM/32), 256, 0, stream>>>(Wqkv, Wqh, Wql, E_DIM, N3);
  transpose_split<<<dim3(E_DIM/32, E_DIM/32), 256, 0, stream>>>(Wo, Woh, Wol, E_DIM, E_DIM);

  gemm3<1><<<dim3(N3/128, M_ROWS/128), 256, 0, stream>>>(
      Xhi, Xlo, Wqh, Wql, E_DIM, N3, nullptr, Qh, Ql_, Kh, Kl, Vth, Vtl);

  attn_kernel<<<dim3(S_LEN/64, NBH), 256, 0, stream>>>(
      Qh, Ql_, Kh, Kl, Vth, Vtl, Ahh, Ahl);

  gemm3<0><<<dim3(E_DIM/128, M_ROWS/128), 256, 0, stream>>>(
      Ahh, Ahl, Woh, Wol, E_DIM, E_DIM, out,
      nullptr, nullptr, nullptr, nullptr, nullptr, nullptr);
}

// Round 3
// 278.878 us; speedup vs baseline: 1.3815x; 1.2310x over previous
//
#include <hip/hip_runtime.h>

typedef float  f32x4  __attribute__((ext_vector_type(4)));
typedef __bf16 bf16x8 __attribute__((ext_vector_type(8)));
typedef short  short8 __attribute__((ext_vector_type(8)));
typedef short  short4v __attribute__((ext_vector_type(4)));

#define MFMA(a,b,c) __builtin_amdgcn_mfma_f32_16x16x32_bf16(a,b,c,0,0,0)

__device__ __forceinline__ short f2bf(float x){
  unsigned u = __builtin_bit_cast(unsigned, x);
  u = (u + 0x7fffu + ((u >> 16) & 1u)) >> 16;   // RNE
  return (short)u;
}
__device__ __forceinline__ float bf2f(short s){
  return __builtin_bit_cast(float, ((unsigned)(unsigned short)s) << 16);
}
__device__ __forceinline__ float exp2_fast(float x){
  float y; asm("v_exp_f32 %0, %1" : "=v"(y) : "v"(x)); return y;
}

#define S_LEN 2048
#define E_DIM 1024
#define H_NUM 16
#define D_DIM 64
#define NBH   32
#define M_ROWS 4096
#define N3    3072
#define LOG2E 1.44269504089f

// ---------------- prep: fp32 -> (hi,lo) bf16 split ----------------
__global__ void split_x_kernel(const float* __restrict__ in,
                               short* __restrict__ hi, short* __restrict__ lo, int n4){
  int i = blockIdx.x * 256 + threadIdx.x;
  if (i >= n4) return;
  const float4 v = reinterpret_cast<const float4*>(in)[i];
  float xs[4] = {v.x, v.y, v.z, v.w};
  short4v h, l;
#pragma unroll
  for (int j = 0; j < 4; ++j){
    short hh = f2bf(xs[j]);
    h[j] = hh;
    l[j] = f2bf(xs[j] - bf2f(hh));
  }
  reinterpret_cast<short4v*>(hi)[i] = h;
  reinterpret_cast<short4v*>(lo)[i] = l;
}

// out[n][k] = in[k][n], split into hi/lo. in is R x C, out is C x R.
__global__ void transpose_split(const float* __restrict__ in,
                                short* __restrict__ hi, short* __restrict__ lo,
                                int R, int C){
  __shared__ float tile[32][33];
  int bx = blockIdx.x * 32, by = blockIdx.y * 32;
  int tx = threadIdx.x & 31, ty = threadIdx.x >> 5;   // 256 threads = 32x8
#pragma unroll
  for (int i = ty; i < 32; i += 8)
    tile[i][tx] = in[(size_t)(by + i) * C + bx + tx];
  __syncthreads();
#pragma unroll
  for (int i = ty; i < 32; i += 8){
    float v = tile[tx][i];
    size_t o = (size_t)(bx + i) * R + by + tx;
    short h = f2bf(v);
    hi[o] = h;
    lo[o] = f2bf(v - bf2f(h));
  }
}

// ---------------- split-bf16 GEMM: C = A @ B^T(rowmajor N x K) ----------------
// A: M x K (hi/lo), B: N x K (hi/lo).  3-term: Ah*Bh + Ah*Bl + Al*Bh.
// EPI=0: write fp32 C (M x Ndim).
// EPI=1: scatter qkv -> Q(*log2e/8)[bh][s][d], K[bh][s][d], V^T[bh][d][s] (V hi only).
template<int EPI>
__global__ __launch_bounds__(256, 2) void gemm3(
    const short* __restrict__ Ah, const short* __restrict__ Al,
    const short* __restrict__ Bh, const short* __restrict__ Bl,
    int Kdim, int Ndim, float* __restrict__ Cout,
    short* __restrict__ qh, short* __restrict__ ql,
    short* __restrict__ kh, short* __restrict__ kl,
    short* __restrict__ vh)
{
  constexpr int LDT = 72;   // 64 + 8 pad
  __shared__ __align__(16) short sAh[128][LDT], sAl[128][LDT], sBh[128][LDT], sBl[128][LDT];
  const int tid = threadIdx.x;
  const int m0 = blockIdx.y * 128, n0 = blockIdx.x * 128;
  const int wid = tid >> 6, lane = tid & 63;
  const int wr = (wid >> 1) * 64, wc = (wid & 1) * 64;
  const int lr = lane & 15, lc = lane >> 4;

  f32x4 acc[4][4] = {};
  const int nK = Kdim >> 6;
  for (int ks = 0; ks < nK; ++ks){
    const int k0 = ks << 6;
#pragma unroll
    for (int p = 0; p < 4; ++p){
      const int i = tid + p * 256;             // 1024 16B chunks per tile
      const int r = i >> 3, c8 = (i & 7) * 8;
      const size_t ga = (size_t)(m0 + r) * Kdim + k0 + c8;
      const size_t gb = (size_t)(n0 + r) * Kdim + k0 + c8;
      *reinterpret_cast<int4*>(&sAh[r][c8]) = *reinterpret_cast<const int4*>(&Ah[ga]);
      *reinterpret_cast<int4*>(&sAl[r][c8]) = *reinterpret_cast<const int4*>(&Al[ga]);
      *reinterpret_cast<int4*>(&sBh[r][c8]) = *reinterpret_cast<const int4*>(&Bh[gb]);
      *reinterpret_cast<int4*>(&sBl[r][c8]) = *reinterpret_cast<const int4*>(&Bl[gb]);
    }
    __syncthreads();
#pragma unroll
    for (int kk = 0; kk < 64; kk += 32){
      bf16x8 fah[4], fal[4], fbh[4], fbl[4];
#pragma unroll
      for (int t = 0; t < 4; ++t){
        fah[t] = *reinterpret_cast<const bf16x8*>(&sAh[wr + t*16 + lr][kk + lc*8]);
        fal[t] = *reinterpret_cast<const bf16x8*>(&sAl[wr + t*16 + lr][kk + lc*8]);
        fbh[t] = *reinterpret_cast<const bf16x8*>(&sBh[wc + t*16 + lr][kk + lc*8]);
        fbl[t] = *reinterpret_cast<const bf16x8*>(&sBl[wc + t*16 + lr][kk + lc*8]);
      }
#pragma unroll
      for (int mt = 0; mt < 4; ++mt)
#pragma unroll
        for (int nt = 0; nt < 4; ++nt){
          f32x4 c = acc[mt][nt];
          c = MFMA(fah[mt], fbh[nt], c);
          c = MFMA(fah[mt], fbl[nt], c);
          c = MFMA(fal[mt], fbh[nt], c);
          acc[mt][nt] = c;
        }
    }
    __syncthreads();
  }
  // epilogue: C/D layout col=lane&15, row=(lane>>4)*4+reg  [m89]
#pragma unroll
  for (int mt = 0; mt < 4; ++mt)
#pragma unroll
    for (int nt = 0; nt < 4; ++nt)
#pragma unroll
      for (int r = 0; r < 4; ++r){
        const int m = m0 + wr + mt*16 + lc*4 + r;
        const int n = n0 + wc + nt*16 + lr;
        float v = acc[mt][nt][r];
        if (EPI == 0){
          Cout[(size_t)m * Ndim + n] = v;
        } else {
          const int t = n >> 10, rem = n & 1023, hh = rem >> 6, d = rem & 63;
          const int b = m >> 11, s = m & 2047;
          const int bh = b * H_NUM + hh;
          if (t == 0) v *= (0.125f * LOG2E);  // fold 1/sqrt(64) and log2(e) into Q
          size_t o;
          if (t == 2)  o = ((size_t)bh * D_DIM + d) * S_LEN + s;   // V transposed
          else         o = ((size_t)bh * S_LEN + s) * D_DIM + d;
          short* ph = (t == 0) ? qh : (t == 1) ? kh : vh;
          const short hv = f2bf(v);
          ph[o] = hv;
          if (t != 2){
            short* pl = (t == 0) ? ql : kl;
            pl[o] = f2bf(v - bf2f(hv));
          }
        }
      }
}

// ---------------- flash attention with ghost softmax ----------------
// WG: (qb, bh). 4 waves x 16 q-rows = 64 q-rows. KV blocks of 64, causal.
// 1-deep reg prefetch of next K/V tile; log2-domain softmax with defer-max.
__global__ __launch_bounds__(256, 4) void attn_kernel(
    const short* __restrict__ Qh, const short* __restrict__ Ql,
    const short* __restrict__ Kh, const short* __restrict__ Kl,
    const short* __restrict__ Vth,
    short* __restrict__ Aoh, short* __restrict__ Aol)
{
  constexpr int LDV = 72;
  __shared__ __align__(16) short sKh[64][LDV], sKl[64][LDV];   // K: [token][d]
  __shared__ __align__(16) short sVh[64][LDV];                 // V^T: [d][token]
  __shared__ __align__(16) short sP[4][16][LDV];               // per-wave P tile [q][token]
  const int tid = threadIdx.x, wid = tid >> 6, lane = tid & 63;
  const int qb = (int)gridDim.x - 1 - (int)blockIdx.x;   // heaviest blocks dispatch first
  const int bh = blockIdx.y;
  const int q0 = qb * 64;
  const int lr = lane & 15, lc = lane >> 4;
  const size_t base = (size_t)bh * S_LEN * D_DIM;        // same size for K and Vt

  // Q fragments (A-operand), hoisted; Q already scaled by log2e/8
  bf16x8 fqh[2], fql[2];
  {
    const int qrow = q0 + wid*16 + lr;
#pragma unroll
    for (int kc = 0; kc < 2; ++kc){
      const size_t o = base + (size_t)qrow * 64 + kc*32 + lc*8;
      fqh[kc] = *reinterpret_cast<const bf16x8*>(&Qh[o]);
      fql[kc] = *reinterpret_cast<const bf16x8*>(&Ql[o]);
    }
  }

  // staging geometry (two 16B chunks per thread per array)
  const int i1 = tid + 256;
  const int r0 = tid >> 3, c80 = (tid & 7) * 8;
  const int r1 = i1 >> 3,  c81 = (i1 & 7) * 8;

  int4 rKh0, rKh1, rKl0, rKl1, rVh0, rVh1;
  auto issue = [&](int t){
    const int kv0 = t * 64;
    const size_t oK0 = base + (size_t)(kv0 + r0) * D_DIM + c80;
    const size_t oK1 = base + (size_t)(kv0 + r1) * D_DIM + c81;
    const size_t oV0 = base + (size_t)r0 * S_LEN + kv0 + c80;
    const size_t oV1 = base + (size_t)r1 * S_LEN + kv0 + c81;
    rKh0 = *reinterpret_cast<const int4*>(&Kh[oK0]);
    rKh1 = *reinterpret_cast<const int4*>(&Kh[oK1]);
    rKl0 = *reinterpret_cast<const int4*>(&Kl[oK0]);
    rKl1 = *reinterpret_cast<const int4*>(&Kl[oK1]);
    rVh0 = *reinterpret_cast<const int4*>(&Vth[oV0]);
    rVh1 = *reinterpret_cast<const int4*>(&Vth[oV1]);
  };

  f32x4 acc[4] = {};
  float mrow[4], lrow[4], tmrow[4];
#pragma unroll
  for (int r = 0; r < 4; ++r){ mrow[r] = -1e30f; lrow[r] = 0.f; tmrow[r] = -1e30f; }

  issue(0);
  for (int t = 0; t <= qb; ++t){
    __syncthreads();   // all waves done reading LDS of previous tile
    *reinterpret_cast<int4*>(&sKh[r0][c80]) = rKh0;
    *reinterpret_cast<int4*>(&sKh[r1][c81]) = rKh1;
    *reinterpret_cast<int4*>(&sKl[r0][c80]) = rKl0;
    *reinterpret_cast<int4*>(&sKl[r1][c81]) = rKl1;
    *reinterpret_cast<int4*>(&sVh[r0][c80]) = rVh0;
    *reinterpret_cast<int4*>(&sVh[r1][c81]) = rVh1;
    if (t < qb) issue(t + 1);   // prefetch next tile; latency hides under compute
    __syncthreads();

    // scores: 3-term split QK^T from LDS (log2 domain)
    f32x4 sc[4];
#pragma unroll
    for (int nt = 0; nt < 4; ++nt){
      f32x4 z = {};
#pragma unroll
      for (int kc = 0; kc < 2; ++kc){
        const bf16x8 fkh = *reinterpret_cast<const bf16x8*>(&sKh[nt*16 + lr][kc*32 + lc*8]);
        const bf16x8 fkl = *reinterpret_cast<const bf16x8*>(&sKl[nt*16 + lr][kc*32 + lc*8]);
        z = MFMA(fqh[kc], fkh, z);
        z = MFMA(fqh[kc], fkl, z);
        z = MFMA(fql[kc], fkh, z);
      }
      sc[nt] = z;
    }

    if (t == qb){   // diagonal block: mask k > q
#pragma unroll
      for (int nt = 0; nt < 4; ++nt)
#pragma unroll
        for (int r = 0; r < 4; ++r)
          if (nt*16 + lr > wid*16 + lc*4 + r) sc[nt][r] = -1e30f;
    }

    // online softmax, defer-max (THR=8 in log2 units)
    float mx4[4];
    int need = 0;
#pragma unroll
    for (int r = 0; r < 4; ++r){
      float mx = fmaxf(fmaxf(sc[0][r], sc[1][r]), fmaxf(sc[2][r], sc[3][r]));
#pragma unroll
      for (int off = 1; off < 16; off <<= 1)
        mx = fmaxf(mx, __shfl_xor(mx, off));
      mx4[r] = mx;
      tmrow[r] = fmaxf(tmrow[r], mx);
      need |= (mx > mrow[r] + 8.0f) ? 1 : 0;
    }
    if (__any(need)){
#pragma unroll
      for (int r = 0; r < 4; ++r){
        const float mn = fmaxf(mrow[r], mx4[r]);
        const float scale = exp2_fast(mrow[r] - mn);
        lrow[r] *= scale;
        mrow[r] = mn;
#pragma unroll
        for (int dt = 0; dt < 4; ++dt) acc[dt][r] *= scale;
      }
    }
#pragma unroll
    for (int r = 0; r < 4; ++r){
      float sum = 0.f;
#pragma unroll
      for (int nt = 0; nt < 4; ++nt){
        const float pv = exp2_fast(sc[nt][r] - mrow[r]);
        sc[nt][r] = pv;
        sum += pv;
      }
#pragma unroll
      for (int off = 1; off < 16; off <<= 1)
        sum += __shfl_xor(sum, off);
      lrow[r] += sum;
    }

    // P (bf16) -> per-wave LDS tile, then read back in A-frag layout
#pragma unroll
    for (int nt = 0; nt < 4; ++nt)
#pragma unroll
      for (int r = 0; r < 4; ++r)
        sP[wid][lc*4 + r][nt*16 + lr] = f2bf(sc[nt][r]);

    bf16x8 pa[2];
#pragma unroll
    for (int kc = 0; kc < 2; ++kc)
      pa[kc] = *reinterpret_cast<const bf16x8*>(&sP[wid][lr][kc*32 + lc*8]);
#pragma unroll
    for (int dt = 0; dt < 4; ++dt){
#pragma unroll
      for (int kc = 0; kc < 2; ++kc){
        const bf16x8 fvh = *reinterpret_cast<const bf16x8*>(&sVh[dt*16 + lr][kc*32 + lc*8]);
        acc[dt] = MFMA(pa[kc], fvh, acc[dt]);
      }
    }
  }

  // finalize: ghost term = 2^(truemax - m); write A hi/lo in (B,S,H*D)
  const int b = bh >> 4, hh = bh & 15;
#pragma unroll
  for (int dt = 0; dt < 4; ++dt)
#pragma unroll
    for (int r = 0; r < 4; ++r){
      const float denom = lrow[r] + exp2_fast(tmrow[r] - mrow[r]);
      const float o = acc[dt][r] / denom;
      const int q = q0 + wid*16 + lc*4 + r;
      const int d = dt*16 + lr;
      const size_t off = ((size_t)(b*S_LEN + q)) * E_DIM + hh*D_DIM + d;
      const short hv = f2bf(o);
      Aoh[off] = hv;
      Aol[off] = f2bf(o - bf2f(hv));
    }
}

// ---------------- launch ----------------
extern "C" void kernel_launch(void* const* d_in, const int* in_sizes, int n_in,
                              void* d_out, int out_size, void* d_ws, size_t ws_size,
                              hipStream_t stream){
  const float* X    = (const float*)d_in[0];
  const float* Wqkv = (const float*)d_in[1];
  const float* Wo   = (const float*)d_in[2];
  float* out = (float*)d_out;

  short* w = (short*)d_ws;
  size_t off = 0;
  auto alloc = [&](size_t n){ short* p = w + off; off += n; return p; };
  const size_t ME   = (size_t)M_ROWS * E_DIM;
  const size_t WQ   = (size_t)N3 * E_DIM;
  const size_t WOsz = (size_t)E_DIM * E_DIM;
  const size_t QK   = (size_t)NBH * S_LEN * D_DIM;
  short *Xhi = alloc(ME), *Xlo = alloc(ME);
  short *Wqh = alloc(WQ), *Wql = alloc(WQ);
  short *Woh = alloc(WOsz), *Wol = alloc(WOsz);
  short *Qh = alloc(QK), *Ql_ = alloc(QK);
  short *Kh = alloc(QK), *Kl  = alloc(QK);
  short *Vth = alloc(QK);
  short *Ahh = alloc(ME), *Ahl = alloc(ME);

  split_x_kernel<<<(int)(ME/4/256), 256, 0, stream>>>(X, Xhi, Xlo, (int)(ME/4));
  transpose_split<<<dim3(N3/32, E_DIM/32), 256, 0, stream>>>(Wqkv, Wqh, Wql, E_DIM, N3);
  transpose_split<<<dim3(E_DIM/32, E_DIM/32), 256, 0, stream>>>(Wo, Woh, Wol, E_DIM, E_DIM);

  gemm3<1><<<dim3(N3/128, M_ROWS/128), 256, 0, stream>>>(
      Xhi, Xlo, Wqh, Wql, E_DIM, N3, nullptr, Qh, Ql_, Kh, Kl, Vth);

  attn_kernel<<<dim3(S_LEN/64, NBH), 256, 0, stream>>>(
      Qh, Ql_, Kh, Kl, Vth, Ahh, Ahl);

  gemm3<0><<<dim3(E_DIM/128, M_ROWS/128), 256, 0, stream>>>(
      Ahh, Ahl, Woh, Wol, E_DIM, E_DIM, out,
      nullptr, nullptr, nullptr, nullptr, nullptr);
}

// Round 4
// 222.715 us; speedup vs baseline: 1.7299x; 1.2522x over previous
//
#include <hip/hip_runtime.h>

typedef float  f32x4  __attribute__((ext_vector_type(4)));
typedef __bf16 bf16x8 __attribute__((ext_vector_type(8)));
typedef short  short8 __attribute__((ext_vector_type(8)));
typedef short  short4v __attribute__((ext_vector_type(4)));

#define MFMA(a,b,c) __builtin_amdgcn_mfma_f32_16x16x32_bf16(a,b,c,0,0,0)

__device__ __forceinline__ short f2bf(float x){
  unsigned u = __builtin_bit_cast(unsigned, x);
  u = (u + 0x7fffu + ((u >> 16) & 1u)) >> 16;   // RNE
  return (short)u;
}
__device__ __forceinline__ float bf2f(short s){
  return __builtin_bit_cast(float, ((unsigned)(unsigned short)s) << 16);
}
__device__ __forceinline__ float exp2_fast(float x){
  float y; asm("v_exp_f32 %0, %1" : "=v"(y) : "v"(x)); return y;
}

// 16-lane-group reductions on the VALU pipe via DPP row_ror (NOT ds_swizzle).
#define DPP_ROR(v,n) __builtin_bit_cast(float, __builtin_amdgcn_update_dpp( \
    __builtin_bit_cast(int,(v)), __builtin_bit_cast(int,(v)), 0x120+(n), 0xF, 0xF, false))
__device__ __forceinline__ float rmax16(float v){
  v = fmaxf(v, DPP_ROR(v,8)); v = fmaxf(v, DPP_ROR(v,4));
  v = fmaxf(v, DPP_ROR(v,2)); v = fmaxf(v, DPP_ROR(v,1));
  return v;
}
__device__ __forceinline__ float rsum16(float v){
  v += DPP_ROR(v,8); v += DPP_ROR(v,4); v += DPP_ROR(v,2); v += DPP_ROR(v,1);
  return v;
}

#define S_LEN 2048
#define E_DIM 1024
#define H_NUM 16
#define D_DIM 64
#define NBH   32
#define M_ROWS 4096
#define N3    3072
#define LOG2E 1.44269504089f

// ---------------- prep: fp32 -> (hi,lo) bf16 split ----------------
__global__ void split_x_kernel(const float* __restrict__ in,
                               short* __restrict__ hi, short* __restrict__ lo, int n4){
  int i = blockIdx.x * 256 + threadIdx.x;
  if (i >= n4) return;
  const float4 v = reinterpret_cast<const float4*>(in)[i];
  float xs[4] = {v.x, v.y, v.z, v.w};
  short4v h, l;
#pragma unroll
  for (int j = 0; j < 4; ++j){
    short hh = f2bf(xs[j]);
    h[j] = hh;
    l[j] = f2bf(xs[j] - bf2f(hh));
  }
  reinterpret_cast<short4v*>(hi)[i] = h;
  reinterpret_cast<short4v*>(lo)[i] = l;
}

// out[n][k] = in[k][n], split into hi/lo. in is R x C, out is C x R.
__global__ void transpose_split(const float* __restrict__ in,
                                short* __restrict__ hi, short* __restrict__ lo,
                                int R, int C){
  __shared__ float tile[32][33];
  int bx = blockIdx.x * 32, by = blockIdx.y * 32;
  int tx = threadIdx.x & 31, ty = threadIdx.x >> 5;   // 256 threads = 32x8
#pragma unroll
  for (int i = ty; i < 32; i += 8)
    tile[i][tx] = in[(size_t)(by + i) * C + bx + tx];
  __syncthreads();
#pragma unroll
  for (int i = ty; i < 32; i += 8){
    float v = tile[tx][i];
    size_t o = (size_t)(bx + i) * R + by + tx;
    short h = f2bf(v);
    hi[o] = h;
    lo[o] = f2bf(v - bf2f(h));
  }
}

// ---------------- split-bf16 GEMM: C = A @ B^T(rowmajor N x K) ----------------
// A: M x K (hi/lo), B: N x K (hi/lo).  3-term: Ah*Bh + Ah*Bl + Al*Bh.
// EPI=0: write fp32 C (M x Ndim).
// EPI=1: scatter qkv -> Q(*log2e/8)[bh][s][d], K[bh][s][d], V^T[bh][d][s] (V hi only).
template<int EPI>
__global__ __launch_bounds__(256, 2) void gemm3(
    const short* __restrict__ Ah, const short* __restrict__ Al,
    const short* __restrict__ Bh, const short* __restrict__ Bl,
    int Kdim, int Ndim, float* __restrict__ Cout,
    short* __restrict__ qh, short* __restrict__ ql,
    short* __restrict__ kh, short* __restrict__ kl,
    short* __restrict__ vh)
{
  constexpr int LDT = 72;   // 64 + 8 pad
  __shared__ __align__(16) short sAh[128][LDT], sAl[128][LDT], sBh[128][LDT], sBl[128][LDT];
  const int tid = threadIdx.x;
  const int m0 = blockIdx.y * 128, n0 = blockIdx.x * 128;
  const int wid = tid >> 6, lane = tid & 63;
  const int wr = (wid >> 1) * 64, wc = (wid & 1) * 64;
  const int lr = lane & 15, lc = lane >> 4;

  f32x4 acc[4][4] = {};
  const int nK = Kdim >> 6;
  for (int ks = 0; ks < nK; ++ks){
    const int k0 = ks << 6;
#pragma unroll
    for (int p = 0; p < 4; ++p){
      const int i = tid + p * 256;             // 1024 16B chunks per tile
      const int r = i >> 3, c8 = (i & 7) * 8;
      const size_t ga = (size_t)(m0 + r) * Kdim + k0 + c8;
      const size_t gb = (size_t)(n0 + r) * Kdim + k0 + c8;
      *reinterpret_cast<int4*>(&sAh[r][c8]) = *reinterpret_cast<const int4*>(&Ah[ga]);
      *reinterpret_cast<int4*>(&sAl[r][c8]) = *reinterpret_cast<const int4*>(&Al[ga]);
      *reinterpret_cast<int4*>(&sBh[r][c8]) = *reinterpret_cast<const int4*>(&Bh[gb]);
      *reinterpret_cast<int4*>(&sBl[r][c8]) = *reinterpret_cast<const int4*>(&Bl[gb]);
    }
    __syncthreads();
#pragma unroll
    for (int kk = 0; kk < 64; kk += 32){
      bf16x8 fah[4], fal[4], fbh[4], fbl[4];
#pragma unroll
      for (int t = 0; t < 4; ++t){
        fah[t] = *reinterpret_cast<const bf16x8*>(&sAh[wr + t*16 + lr][kk + lc*8]);
        fal[t] = *reinterpret_cast<const bf16x8*>(&sAl[wr + t*16 + lr][kk + lc*8]);
        fbh[t] = *reinterpret_cast<const bf16x8*>(&sBh[wc + t*16 + lr][kk + lc*8]);
        fbl[t] = *reinterpret_cast<const bf16x8*>(&sBl[wc + t*16 + lr][kk + lc*8]);
      }
#pragma unroll
      for (int mt = 0; mt < 4; ++mt)
#pragma unroll
        for (int nt = 0; nt < 4; ++nt){
          f32x4 c = acc[mt][nt];
          c = MFMA(fah[mt], fbh[nt], c);
          c = MFMA(fah[mt], fbl[nt], c);
          c = MFMA(fal[mt], fbh[nt], c);
          acc[mt][nt] = c;
        }
    }
    __syncthreads();
  }
  // epilogue: C/D layout col=lane&15, row=(lane>>4)*4+reg  [m89]
#pragma unroll
  for (int mt = 0; mt < 4; ++mt)
#pragma unroll
    for (int nt = 0; nt < 4; ++nt)
#pragma unroll
      for (int r = 0; r < 4; ++r){
        const int m = m0 + wr + mt*16 + lc*4 + r;
        const int n = n0 + wc + nt*16 + lr;
        float v = acc[mt][nt][r];
        if (EPI == 0){
          Cout[(size_t)m * Ndim + n] = v;
        } else {
          const int t = n >> 10, rem = n & 1023, hh = rem >> 6, d = rem & 63;
          const int b = m >> 11, s = m & 2047;
          const int bh = b * H_NUM + hh;
          if (t == 0) v *= (0.125f * LOG2E);  // fold 1/sqrt(64) and log2(e) into Q
          size_t o;
          if (t == 2)  o = ((size_t)bh * D_DIM + d) * S_LEN + s;   // V transposed
          else         o = ((size_t)bh * S_LEN + s) * D_DIM + d;
          short* ph = (t == 0) ? qh : (t == 1) ? kh : vh;
          const short hv = f2bf(v);
          ph[o] = hv;
          if (t != 2){
            short* pl = (t == 0) ? ql : kl;
            pl[o] = f2bf(v - bf2f(hv));
          }
        }
      }
}

// ---------------- flash attention with ghost softmax ----------------
// WG: (pair, bh). Each block does q-tiles (31-p) then (p): exactly 33 KV-iters.
// 4 waves x 16 q-rows. Double-buffered K/V LDS, 1 barrier/iter, reg prefetch,
// DPP (VALU-pipe) reductions, log2-domain softmax with defer-max.
__global__ __launch_bounds__(256, 2) void attn_kernel(
    const short* __restrict__ Qh, const short* __restrict__ Ql,
    const short* __restrict__ Kh, const short* __restrict__ Kl,
    const short* __restrict__ Vth,
    short* __restrict__ Aoh, short* __restrict__ Aol)
{
  constexpr int LDV = 72;
  __shared__ __align__(16) short sKh[2][64][LDV], sKl[2][64][LDV], sVh[2][64][LDV];
  __shared__ __align__(16) short sP[4][16][LDV];               // per-wave P tile [q][token]
  const int tid = threadIdx.x, wid = tid >> 6, lane = tid & 63;
  const int pr = blockIdx.x;            // 0..15
  const int bh = blockIdx.y;
  const int lr = lane & 15, lc = lane >> 4;
  const size_t base = (size_t)bh * S_LEN * D_DIM;

  // staging geometry (two 16B chunks per thread per array)
  const int i1 = tid + 256;
  const int r0 = tid >> 3, c80 = (tid & 7) * 8;
  const int r1 = i1 >> 3,  c81 = (i1 & 7) * 8;

  int4 rKh0, rKh1, rKl0, rKl1, rVh0, rVh1;
  auto issue = [&](int t){
    const int kv0 = t * 64;
    const size_t oK0 = base + (size_t)(kv0 + r0) * D_DIM + c80;
    const size_t oK1 = base + (size_t)(kv0 + r1) * D_DIM + c81;
    const size_t oV0 = base + (size_t)r0 * S_LEN + kv0 + c80;
    const size_t oV1 = base + (size_t)r1 * S_LEN + kv0 + c81;
    rKh0 = *reinterpret_cast<const int4*>(&Kh[oK0]);
    rKh1 = *reinterpret_cast<const int4*>(&Kh[oK1]);
    rKl0 = *reinterpret_cast<const int4*>(&Kl[oK0]);
    rKl1 = *reinterpret_cast<const int4*>(&Kl[oK1]);
    rVh0 = *reinterpret_cast<const int4*>(&Vth[oV0]);
    rVh1 = *reinterpret_cast<const int4*>(&Vth[oV1]);
  };
  auto store = [&](int buf){
    *reinterpret_cast<int4*>(&sKh[buf][r0][c80]) = rKh0;
    *reinterpret_cast<int4*>(&sKh[buf][r1][c81]) = rKh1;
    *reinterpret_cast<int4*>(&sKl[buf][r0][c80]) = rKl0;
    *reinterpret_cast<int4*>(&sKl[buf][r1][c81]) = rKl1;
    *reinterpret_cast<int4*>(&sVh[buf][r0][c80]) = rVh0;
    *reinterpret_cast<int4*>(&sVh[buf][r1][c81]) = rVh1;
  };

  const int b = bh >> 4, hh = bh & 15;

  for (int half = 0; half < 2; ++half){
    const int qt = half ? pr : (31 - pr);
    const int q0 = qt * 64;
    const int nT = qt + 1;

    // Q fragments (A-operand), hoisted; Q already scaled by log2e/8
    bf16x8 fqh[2], fql[2];
    {
      const int qrow = q0 + wid*16 + lr;
#pragma unroll
      for (int kc = 0; kc < 2; ++kc){
        const size_t o = base + (size_t)qrow * 64 + kc*32 + lc*8;
        fqh[kc] = *reinterpret_cast<const bf16x8*>(&Qh[o]);
        fql[kc] = *reinterpret_cast<const bf16x8*>(&Ql[o]);
      }
    }

    f32x4 acc[4] = {};
    float mrow[4], lrow[4], tmrow[4];
#pragma unroll
    for (int r = 0; r < 4; ++r){ mrow[r] = -1e30f; lrow[r] = 0.f; tmrow[r] = -1e30f; }

    // prologue: fill buf0 with tile 0, prefetch tile 1 into regs
    issue(0);
    __syncthreads();          // prev half's LDS reads complete
    store(0);
    if (nT > 1) issue(1);
    __syncthreads();

    int cur = 0;
    for (int t = 0; t < nT; ++t){
      // regs hold tile t+1 -> write to back buffer, then prefetch t+2
      if (t + 1 < nT){
        store(cur ^ 1);
        if (t + 2 < nT) issue(t + 2);
      }

      // scores: 3-term split QK^T from LDS (log2 domain)
      f32x4 sc[4];
#pragma unroll
      for (int nt = 0; nt < 4; ++nt){
        f32x4 z = {};
#pragma unroll
        for (int kc = 0; kc < 2; ++kc){
          const bf16x8 fkh = *reinterpret_cast<const bf16x8*>(&sKh[cur][nt*16 + lr][kc*32 + lc*8]);
          const bf16x8 fkl = *reinterpret_cast<const bf16x8*>(&sKl[cur][nt*16 + lr][kc*32 + lc*8]);
          z = MFMA(fqh[kc], fkh, z);
          z = MFMA(fqh[kc], fkl, z);
          z = MFMA(fql[kc], fkh, z);
        }
        sc[nt] = z;
      }

      if (t == qt){   // diagonal block: mask k > q
#pragma unroll
        for (int nt = 0; nt < 4; ++nt)
#pragma unroll
          for (int r = 0; r < 4; ++r)
            if (nt*16 + lr > wid*16 + lc*4 + r) sc[nt][r] = -1e30f;
      }

      // online softmax, defer-max (THR=8 in log2 units); DPP reductions
      float mx4[4];
      int need = 0;
#pragma unroll
      for (int r = 0; r < 4; ++r){
        float mx = fmaxf(fmaxf(sc[0][r], sc[1][r]), fmaxf(sc[2][r], sc[3][r]));
        mx = rmax16(mx);
        mx4[r] = mx;
        tmrow[r] = fmaxf(tmrow[r], mx);
        need |= (mx > mrow[r] + 8.0f) ? 1 : 0;
      }
      if (__any(need)){
#pragma unroll
        for (int r = 0; r < 4; ++r){
          const float mn = fmaxf(mrow[r], mx4[r]);
          const float scale = exp2_fast(mrow[r] - mn);
          lrow[r] *= scale;
          mrow[r] = mn;
#pragma unroll
          for (int dt = 0; dt < 4; ++dt) acc[dt][r] *= scale;
        }
      }
#pragma unroll
      for (int r = 0; r < 4; ++r){
        float sum = 0.f;
#pragma unroll
        for (int nt = 0; nt < 4; ++nt){
          const float pv = exp2_fast(sc[nt][r] - mrow[r]);
          sc[nt][r] = pv;
          sum += pv;
        }
        lrow[r] += rsum16(sum);
      }

      // P (bf16) -> per-wave LDS tile, then read back in A-frag layout
#pragma unroll
      for (int nt = 0; nt < 4; ++nt)
#pragma unroll
        for (int r = 0; r < 4; ++r)
          sP[wid][lc*4 + r][nt*16 + lr] = f2bf(sc[nt][r]);

      bf16x8 pa[2];
#pragma unroll
      for (int kc = 0; kc < 2; ++kc)
        pa[kc] = *reinterpret_cast<const bf16x8*>(&sP[wid][lr][kc*32 + lc*8]);
#pragma unroll
      for (int dt = 0; dt < 4; ++dt){
#pragma unroll
        for (int kc = 0; kc < 2; ++kc){
          const bf16x8 fvh = *reinterpret_cast<const bf16x8*>(&sVh[cur][dt*16 + lr][kc*32 + lc*8]);
          acc[dt] = MFMA(pa[kc], fvh, acc[dt]);
        }
      }

      __syncthreads();   // back buffer written by all, front buffer reads done
      cur ^= 1;
    }

    // finalize: ghost term = 2^(truemax - m); write A hi/lo in (B,S,H*D)
#pragma unroll
    for (int dt = 0; dt < 4; ++dt)
#pragma unroll
      for (int r = 0; r < 4; ++r){
        const float denom = lrow[r] + exp2_fast(tmrow[r] - mrow[r]);
        const float o = acc[dt][r] / denom;
        const int q = q0 + wid*16 + lc*4 + r;
        const int d = dt*16 + lr;
        const size_t off = ((size_t)(b*S_LEN + q)) * E_DIM + hh*D_DIM + d;
        const short hv = f2bf(o);
        Aoh[off] = hv;
        Aol[off] = f2bf(o - bf2f(hv));
      }
  }
}

// ---------------- launch ----------------
extern "C" void kernel_launch(void* const* d_in, const int* in_sizes, int n_in,
                              void* d_out, int out_size, void* d_ws, size_t ws_size,
                              hipStream_t stream){
  const float* X    = (const float*)d_in[0];
  const float* Wqkv = (const float*)d_in[1];
  const float* Wo   = (const float*)d_in[2];
  float* out = (float*)d_out;

  short* w = (short*)d_ws;
  size_t off = 0;
  auto alloc = [&](size_t n){ short* p = w + off; off += n; return p; };
  const size_t ME   = (size_t)M_ROWS * E_DIM;
  const size_t WQ   = (size_t)N3 * E_DIM;
  const size_t WOsz = (size_t)E_DIM * E_DIM;
  const size_t QK   = (size_t)NBH * S_LEN * D_DIM;
  short *Xhi = alloc(ME), *Xlo = alloc(ME);
  short *Wqh = alloc(WQ), *Wql = alloc(WQ);
  short *Woh = alloc(WOsz), *Wol = alloc(WOsz);
  short *Qh = alloc(QK), *Ql_ = alloc(QK);
  short *Kh = alloc(QK), *Kl  = alloc(QK);
  short *Vth = alloc(QK);
  short *Ahh = alloc(ME), *Ahl = alloc(ME);

  split_x_kernel<<<(int)(ME/4/256), 256, 0, stream>>>(X, Xhi, Xlo, (int)(ME/4));
  transpose_split<<<dim3(N3/32, E_DIM/32), 256, 0, stream>>>(Wqkv, Wqh, Wql, E_DIM, N3);
  transpose_split<<<dim3(E_DIM/32, E_DIM/32), 256, 0, stream>>>(Wo, Woh, Wol, E_DIM, E_DIM);

  gemm3<1><<<dim3(N3/128, M_ROWS/128), 256, 0, stream>>>(
      Xhi, Xlo, Wqh, Wql, E_DIM, N3, nullptr, Qh, Ql_, Kh, Kl, Vth);

  attn_kernel<<<dim3(16, NBH), 256, 0, stream>>>(
      Qh, Ql_, Kh, Kl, Vth, Ahh, Ahl);

  gemm3<0><<<dim3(E_DIM/128, M_ROWS/128), 256, 0, stream>>>(
      Ahh, Ahl, Woh, Wol, E_DIM, E_DIM, out,
      nullptr, nullptr, nullptr, nullptr, nullptr);
}

// Round 5
// 182.212 us; speedup vs baseline: 2.1145x; 1.2223x over previous
//
#include <hip/hip_runtime.h>

typedef float    f32x4  __attribute__((ext_vector_type(4)));
typedef _Float16 half8  __attribute__((ext_vector_type(8)));
typedef _Float16 half4v __attribute__((ext_vector_type(4)));

#define MFMA16(a,b,c) __builtin_amdgcn_mfma_f32_16x16x32_f16(a,b,c,0,0,0)

__device__ __forceinline__ float exp2_fast(float x){
  float y; asm("v_exp_f32 %0, %1" : "=v"(y) : "v"(x)); return y;
}

// 16-lane-group reductions on the VALU pipe via DPP row_ror (NOT ds_swizzle).
#define DPP_ROR(v,n) __builtin_bit_cast(float, __builtin_amdgcn_update_dpp( \
    __builtin_bit_cast(int,(v)), __builtin_bit_cast(int,(v)), 0x120+(n), 0xF, 0xF, false))
__device__ __forceinline__ float rmax16(float v){
  v = fmaxf(v, DPP_ROR(v,8)); v = fmaxf(v, DPP_ROR(v,4));
  v = fmaxf(v, DPP_ROR(v,2)); v = fmaxf(v, DPP_ROR(v,1));
  return v;
}
__device__ __forceinline__ float rsum16(float v){
  v += DPP_ROR(v,8); v += DPP_ROR(v,4); v += DPP_ROR(v,2); v += DPP_ROR(v,1);
  return v;
}

#define S_LEN 2048
#define E_DIM 1024
#define H_NUM 16
#define D_DIM 64
#define NBH   32
#define M_ROWS 4096
#define N3    3072
#define LOG2E 1.44269504089f

// ---------------- prep: fp32 -> (hi,lo) fp16 split ----------------
__global__ void split_x_kernel(const float* __restrict__ in,
                               _Float16* __restrict__ hi, _Float16* __restrict__ lo, int n4){
  int i = blockIdx.x * 256 + threadIdx.x;
  if (i >= n4) return;
  const float4 v = reinterpret_cast<const float4*>(in)[i];
  float xs[4] = {v.x, v.y, v.z, v.w};
  half4v h, l;
#pragma unroll
  for (int j = 0; j < 4; ++j){
    _Float16 hh = (_Float16)xs[j];
    h[j] = hh;
    l[j] = (_Float16)(xs[j] - (float)hh);
  }
  *reinterpret_cast<half4v*>(&hi[i*4]) = h;
  *reinterpret_cast<half4v*>(&lo[i*4]) = l;
}

// out[n][k] = in[k][n], single fp16. in is R x C, out is C x R.
__global__ void transpose_half(const float* __restrict__ in,
                               _Float16* __restrict__ hi, int R, int C){
  __shared__ float tile[32][33];
  int bx = blockIdx.x * 32, by = blockIdx.y * 32;
  int tx = threadIdx.x & 31, ty = threadIdx.x >> 5;   // 256 threads = 32x8
#pragma unroll
  for (int i = ty; i < 32; i += 8)
    tile[i][tx] = in[(size_t)(by + i) * C + bx + tx];
  __syncthreads();
#pragma unroll
  for (int i = ty; i < 32; i += 8)
    hi[(size_t)(bx + i) * R + by + tx] = (_Float16)tile[tx][i];
}

// ---------------- fp16 GEMM: C = A @ B^T(rowmajor N x K) ----------------
// TERMS=2: A split hi/lo, C = Ah*B + Al*B.  TERMS=1: plain fp16 GEMM.
// EPI=0: write fp32 C. EPI=1: scatter qkv -> Q(*log2e/8)[bh][s][d], K[bh][s][d], V^T[bh][d][s].
template<int EPI, int TERMS>
__global__ __launch_bounds__(256, TERMS==2 ? 2 : 4) void gemm3(
    const _Float16* __restrict__ Ah, const _Float16* __restrict__ Al,
    const _Float16* __restrict__ Bh,
    int Kdim, int Ndim, float* __restrict__ Cout,
    _Float16* __restrict__ qh, _Float16* __restrict__ kh, _Float16* __restrict__ vh)
{
  constexpr int LDT = 72;   // 64 + 8 pad (halfs): 144B rows
  __shared__ __align__(16) _Float16 sAh[128][LDT];
  __shared__ __align__(16) _Float16 sAl[TERMS==2 ? 128 : 1][LDT];
  __shared__ __align__(16) _Float16 sBh[128][LDT];
  const int tid = threadIdx.x;
  const int m0 = blockIdx.y * 128, n0 = blockIdx.x * 128;
  const int wid = tid >> 6, lane = tid & 63;
  const int wr = (wid >> 1) * 64, wc = (wid & 1) * 64;
  const int lr = lane & 15, lc = lane >> 4;

  f32x4 acc[4][4] = {};
  const int nK = Kdim >> 6;
  for (int ks = 0; ks < nK; ++ks){
    const int k0 = ks << 6;
#pragma unroll
    for (int p = 0; p < 4; ++p){
      const int i = tid + p * 256;             // 1024 16B chunks per tile
      const int r = i >> 3, c8 = (i & 7) * 8;
      const size_t ga = (size_t)(m0 + r) * Kdim + k0 + c8;
      const size_t gb = (size_t)(n0 + r) * Kdim + k0 + c8;
      *reinterpret_cast<int4*>(&sAh[r][c8]) = *reinterpret_cast<const int4*>(&Ah[ga]);
      if (TERMS == 2)
        *reinterpret_cast<int4*>(&sAl[r][c8]) = *reinterpret_cast<const int4*>(&Al[ga]);
      *reinterpret_cast<int4*>(&sBh[r][c8]) = *reinterpret_cast<const int4*>(&Bh[gb]);
    }
    __syncthreads();
#pragma unroll
    for (int kk = 0; kk < 64; kk += 32){
      half8 fah[4], fal[4], fbh[4];
#pragma unroll
      for (int t = 0; t < 4; ++t){
        fah[t] = *reinterpret_cast<const half8*>(&sAh[wr + t*16 + lr][kk + lc*8]);
        if (TERMS == 2)
          fal[t] = *reinterpret_cast<const half8*>(&sAl[wr + t*16 + lr][kk + lc*8]);
        fbh[t] = *reinterpret_cast<const half8*>(&sBh[wc + t*16 + lr][kk + lc*8]);
      }
#pragma unroll
      for (int mt = 0; mt < 4; ++mt)
#pragma unroll
        for (int nt = 0; nt < 4; ++nt){
          f32x4 c = acc[mt][nt];
          c = MFMA16(fah[mt], fbh[nt], c);
          if (TERMS == 2) c = MFMA16(fal[mt], fbh[nt], c);
          acc[mt][nt] = c;
        }
    }
    __syncthreads();
  }
  // epilogue: C/D layout col=lane&15, row=(lane>>4)*4+reg  [m89]
#pragma unroll
  for (int mt = 0; mt < 4; ++mt)
#pragma unroll
    for (int nt = 0; nt < 4; ++nt)
#pragma unroll
      for (int r = 0; r < 4; ++r){
        const int m = m0 + wr + mt*16 + lc*4 + r;
        const int n = n0 + wc + nt*16 + lr;
        float v = acc[mt][nt][r];
        if (EPI == 0){
          Cout[(size_t)m * Ndim + n] = v;
        } else {
          const int t = n >> 10, rem = n & 1023, hh = rem >> 6, d = rem & 63;
          const int b = m >> 11, s = m & 2047;
          const int bh = b * H_NUM + hh;
          if (t == 0) v *= (0.125f * LOG2E);  // fold 1/sqrt(64) and log2(e) into Q
          size_t o;
          if (t == 2)  o = ((size_t)bh * D_DIM + d) * S_LEN + s;   // V transposed
          else         o = ((size_t)bh * S_LEN + s) * D_DIM + d;
          _Float16* ph = (t == 0) ? qh : (t == 1) ? kh : vh;
          ph[o] = (_Float16)v;
        }
      }
}

// ---------------- flash attention with ghost softmax (all fp16) ----------------
// WG: (pair, bh). Each block does q-tiles (31-p) then (p): exactly 33 KV-iters.
// 4 waves x 16 q-rows. Double-buffered K/V LDS, 1 barrier/iter, reg prefetch,
// DPP (VALU-pipe) reductions, log2-domain softmax with defer-max.
__global__ __launch_bounds__(256, 2) void attn_kernel(
    const _Float16* __restrict__ Qh, const _Float16* __restrict__ Kh,
    const _Float16* __restrict__ Vth, _Float16* __restrict__ Ao)
{
  constexpr int LDV = 72;
  __shared__ __align__(16) _Float16 sKh[2][64][LDV], sVh[2][64][LDV];
  __shared__ __align__(16) _Float16 sP[4][16][LDV];            // per-wave P tile [q][token]
  const int tid = threadIdx.x, wid = tid >> 6, lane = tid & 63;
  const int pr = blockIdx.x;            // 0..15
  const int bh = blockIdx.y;
  const int lr = lane & 15, lc = lane >> 4;
  const size_t base = (size_t)bh * S_LEN * D_DIM;

  // staging geometry (two 16B chunks per thread per array)
  const int i1 = tid + 256;
  const int r0 = tid >> 3, c80 = (tid & 7) * 8;
  const int r1 = i1 >> 3,  c81 = (i1 & 7) * 8;

  int4 rK0, rK1, rV0, rV1;
  auto issue = [&](int t){
    const int kv0 = t * 64;
    rK0 = *reinterpret_cast<const int4*>(&Kh[base + (size_t)(kv0 + r0) * D_DIM + c80]);
    rK1 = *reinterpret_cast<const int4*>(&Kh[base + (size_t)(kv0 + r1) * D_DIM + c81]);
    rV0 = *reinterpret_cast<const int4*>(&Vth[base + (size_t)r0 * S_LEN + kv0 + c80]);
    rV1 = *reinterpret_cast<const int4*>(&Vth[base + (size_t)r1 * S_LEN + kv0 + c81]);
  };
  auto store = [&](int buf){
    *reinterpret_cast<int4*>(&sKh[buf][r0][c80]) = rK0;
    *reinterpret_cast<int4*>(&sKh[buf][r1][c81]) = rK1;
    *reinterpret_cast<int4*>(&sVh[buf][r0][c80]) = rV0;
    *reinterpret_cast<int4*>(&sVh[buf][r1][c81]) = rV1;
  };

  const int b = bh >> 4, hh = bh & 15;

  for (int half = 0; half < 2; ++half){
    const int qt = half ? pr : (31 - pr);
    const int q0 = qt * 64;
    const int nT = qt + 1;

    // Q fragments (A-operand), hoisted; Q already scaled by log2e/8
    half8 fq[2];
    {
      const int qrow = q0 + wid*16 + lr;
#pragma unroll
      for (int kc = 0; kc < 2; ++kc)
        fq[kc] = *reinterpret_cast<const half8*>(&Qh[base + (size_t)qrow * 64 + kc*32 + lc*8]);
    }

    f32x4 acc[4] = {};
    float mrow[4], lrow[4], tmrow[4];
#pragma unroll
    for (int r = 0; r < 4; ++r){ mrow[r] = -1e30f; lrow[r] = 0.f; tmrow[r] = -1e30f; }

    // prologue: fill buf0 with tile 0, prefetch tile 1 into regs
    issue(0);
    __syncthreads();          // prev half's LDS reads complete
    store(0);
    if (nT > 1) issue(1);
    __syncthreads();

    int cur = 0;
    for (int t = 0; t < nT; ++t){
      // regs hold tile t+1 -> write to back buffer, then prefetch t+2
      if (t + 1 < nT){
        store(cur ^ 1);
        if (t + 2 < nT) issue(t + 2);
      }

      // scores: QK^T from LDS (log2 domain), single-term fp16
      f32x4 sc[4];
#pragma unroll
      for (int nt = 0; nt < 4; ++nt){
        f32x4 z = {};
#pragma unroll
        for (int kc = 0; kc < 2; ++kc){
          const half8 fk = *reinterpret_cast<const half8*>(&sKh[cur][nt*16 + lr][kc*32 + lc*8]);
          z = MFMA16(fq[kc], fk, z);
        }
        sc[nt] = z;
      }

      if (t == qt){   // diagonal block: mask k > q
#pragma unroll
        for (int nt = 0; nt < 4; ++nt)
#pragma unroll
          for (int r = 0; r < 4; ++r)
            if (nt*16 + lr > wid*16 + lc*4 + r) sc[nt][r] = -1e30f;
      }

      // online softmax, defer-max (THR=8 in log2 units); DPP reductions
      float mx4[4];
      int need = 0;
#pragma unroll
      for (int r = 0; r < 4; ++r){
        float mx = fmaxf(fmaxf(sc[0][r], sc[1][r]), fmaxf(sc[2][r], sc[3][r]));
        mx = rmax16(mx);
        mx4[r] = mx;
        tmrow[r] = fmaxf(tmrow[r], mx);
        need |= (mx > mrow[r] + 8.0f) ? 1 : 0;
      }
      if (__any(need)){
#pragma unroll
        for (int r = 0; r < 4; ++r){
          const float mn = fmaxf(mrow[r], mx4[r]);
          const float scale = exp2_fast(mrow[r] - mn);
          lrow[r] *= scale;
          mrow[r] = mn;
#pragma unroll
          for (int dt = 0; dt < 4; ++dt) acc[dt][r] *= scale;
        }
      }
#pragma unroll
      for (int r = 0; r < 4; ++r){
        float sum = 0.f;
#pragma unroll
        for (int nt = 0; nt < 4; ++nt){
          const float pv = exp2_fast(sc[nt][r] - mrow[r]);
          sc[nt][r] = pv;
          sum += pv;
        }
        lrow[r] += rsum16(sum);
      }

      // P (fp16) -> per-wave LDS tile, then read back in A-frag layout
#pragma unroll
      for (int nt = 0; nt < 4; ++nt)
#pragma unroll
        for (int r = 0; r < 4; ++r)
          sP[wid][lc*4 + r][nt*16 + lr] = (_Float16)sc[nt][r];

      half8 pa[2];
#pragma unroll
      for (int kc = 0; kc < 2; ++kc)
        pa[kc] = *reinterpret_cast<const half8*>(&sP[wid][lr][kc*32 + lc*8]);
#pragma unroll
      for (int dt = 0; dt < 4; ++dt){
#pragma unroll
        for (int kc = 0; kc < 2; ++kc){
          const half8 fv = *reinterpret_cast<const half8*>(&sVh[cur][dt*16 + lr][kc*32 + lc*8]);
          acc[dt] = MFMA16(pa[kc], fv, acc[dt]);
        }
      }

      __syncthreads();   // back buffer written by all, front buffer reads done
      cur ^= 1;
    }

    // finalize: ghost term = 2^(truemax - m); write A fp16 in (B,S,H*D)
#pragma unroll
    for (int dt = 0; dt < 4; ++dt)
#pragma unroll
      for (int r = 0; r < 4; ++r){
        const float denom = lrow[r] + exp2_fast(tmrow[r] - mrow[r]);
        const float o = acc[dt][r] / denom;
        const int q = q0 + wid*16 + lc*4 + r;
        const int d = dt*16 + lr;
        Ao[((size_t)(b*S_LEN + q)) * E_DIM + hh*D_DIM + d] = (_Float16)o;
      }
  }
}

// ---------------- launch ----------------
extern "C" void kernel_launch(void* const* d_in, const int* in_sizes, int n_in,
                              void* d_out, int out_size, void* d_ws, size_t ws_size,
                              hipStream_t stream){
  const float* X    = (const float*)d_in[0];
  const float* Wqkv = (const float*)d_in[1];
  const float* Wo   = (const float*)d_in[2];
  float* out = (float*)d_out;

  _Float16* w = (_Float16*)d_ws;
  size_t off = 0;
  auto alloc = [&](size_t n){ _Float16* p = w + off; off += n; return p; };
  const size_t ME   = (size_t)M_ROWS * E_DIM;
  const size_t WQ   = (size_t)N3 * E_DIM;
  const size_t WOsz = (size_t)E_DIM * E_DIM;
  const size_t QK   = (size_t)NBH * S_LEN * D_DIM;
  _Float16 *Xh = alloc(ME), *Xl = alloc(ME);
  _Float16 *Wqh = alloc(WQ);
  _Float16 *Woh = alloc(WOsz);
  _Float16 *Qh = alloc(QK), *Kh = alloc(QK), *Vth = alloc(QK);
  _Float16 *Ahalf = alloc(ME);

  split_x_kernel<<<(int)(ME/4/256), 256, 0, stream>>>(X, Xh, Xl, (int)(ME/4));
  transpose_half<<<dim3(N3/32, E_DIM/32), 256, 0, stream>>>(Wqkv, Wqh, E_DIM, N3);
  transpose_half<<<dim3(E_DIM/32, E_DIM/32), 256, 0, stream>>>(Wo, Woh, E_DIM, E_DIM);

  gemm3<1,2><<<dim3(N3/128, M_ROWS/128), 256, 0, stream>>>(
      Xh, Xl, Wqh, E_DIM, N3, nullptr, Qh, Kh, Vth);

  attn_kernel<<<dim3(16, NBH), 256, 0, stream>>>(Qh, Kh, Vth, Ahalf);

  gemm3<0,1><<<dim3(E_DIM/128, M_ROWS/128), 256, 0, stream>>>(
      Ahalf, nullptr, Woh, E_DIM, E_DIM, out, nullptr, nullptr, nullptr);
}

// Round 6
// 142.259 us; speedup vs baseline: 2.7083x; 1.2808x over previous
//
#include <hip/hip_runtime.h>

typedef float    f32x4  __attribute__((ext_vector_type(4)));
typedef _Float16 half8  __attribute__((ext_vector_type(8)));
typedef _Float16 half4v __attribute__((ext_vector_type(4)));

#define MFMA16(a,b,c) __builtin_amdgcn_mfma_f32_16x16x32_f16(a,b,c,0,0,0)

__device__ __forceinline__ float exp2_fast(float x){
  float y; asm("v_exp_f32 %0, %1" : "=v"(y) : "v"(x)); return y;
}
// async global->LDS, 16B per lane; LDS dest is wave-uniform base + lane*16
__device__ __forceinline__ void gload_lds16(const _Float16* g, _Float16* l){
  __builtin_amdgcn_global_load_lds(
      (const __attribute__((address_space(1))) unsigned int*)(g),
      (__attribute__((address_space(3))) unsigned int*)(l),
      16, 0, 0);
}

// 16-lane-group reductions on the VALU pipe via DPP row_ror (NOT ds_swizzle).
#define DPP_ROR(v,n) __builtin_bit_cast(float, __builtin_amdgcn_update_dpp( \
    __builtin_bit_cast(int,(v)), __builtin_bit_cast(int,(v)), 0x120+(n), 0xF, 0xF, false))
__device__ __forceinline__ float rmax16(float v){
  v = fmaxf(v, DPP_ROR(v,8)); v = fmaxf(v, DPP_ROR(v,4));
  v = fmaxf(v, DPP_ROR(v,2)); v = fmaxf(v, DPP_ROR(v,1));
  return v;
}
__device__ __forceinline__ float rsum16(float v){
  v += DPP_ROR(v,8); v += DPP_ROR(v,4); v += DPP_ROR(v,2); v += DPP_ROR(v,1);
  return v;
}

#define S_LEN 2048
#define E_DIM 1024
#define H_NUM 16
#define D_DIM 64
#define NBH   32
#define M_ROWS 4096
#define N3    3072
#define LOG2E 1.44269504089f

// ---------------- prep: fp32 -> fp16 cast ----------------
__global__ void cast_x_kernel(const float* __restrict__ in,
                              _Float16* __restrict__ hi, int n4){
  int i = blockIdx.x * 256 + threadIdx.x;
  if (i >= n4) return;
  const float4 v = reinterpret_cast<const float4*>(in)[i];
  half4v h;
  h[0] = (_Float16)v.x; h[1] = (_Float16)v.y;
  h[2] = (_Float16)v.z; h[3] = (_Float16)v.w;
  *reinterpret_cast<half4v*>(&hi[i*4]) = h;
}

// out[n][k] = in[k][n], single fp16. in is R x C, out is C x R.
__global__ void transpose_half(const float* __restrict__ in,
                               _Float16* __restrict__ hi, int R, int C){
  __shared__ float tile[32][33];
  int bx = blockIdx.x * 32, by = blockIdx.y * 32;
  int tx = threadIdx.x & 31, ty = threadIdx.x >> 5;   // 256 threads = 32x8
#pragma unroll
  for (int i = ty; i < 32; i += 8)
    tile[i][tx] = in[(size_t)(by + i) * C + bx + tx];
  __syncthreads();
#pragma unroll
  for (int i = ty; i < 32; i += 8)
    hi[(size_t)(bx + i) * R + by + tx] = (_Float16)tile[tx][i];
}

// ---------------- fp16 GEMM (m97 structure): C = A @ B^T(rowmajor N x K) ----
// 128x128 tile, BK=64, 4 waves, global_load_lds staging, linear LDS.
// EPI=0: write fp32 C. EPI=1: scatter qkv -> Q(*log2e/8)[bh][s][d], K[bh][s][d], V^T[bh][d][s].
template<int EPI>
__global__ __launch_bounds__(256, 3) void gemm97(
    const _Float16* __restrict__ A, const _Float16* __restrict__ B,
    int Kdim, int Ndim, float* __restrict__ Cout,
    _Float16* __restrict__ qh, _Float16* __restrict__ kh, _Float16* __restrict__ vh)
{
  __shared__ __align__(16) _Float16 sA[128][64], sB[128][64];
  const int tid = threadIdx.x;
  const int m0 = blockIdx.y * 128, n0 = blockIdx.x * 128;
  const int wid = tid >> 6, lane = tid & 63;
  const int wr = (wid >> 1) * 64, wc = (wid & 1) * 64;
  const int lr = lane & 15, lc = lane >> 4;
  const int ldrow = lane >> 3, ldcol = (lane & 7) * 8;   // lane's slot within a 1KB chunk

  f32x4 acc[4][4] = {};
  const int nK = Kdim >> 6;
  for (int ks = 0; ks < nK; ++ks){
    const int k0 = ks << 6;
    // stage A,B tiles: 16 chunks each (8 rows/chunk), 4 per wave per array
#pragma unroll
    for (int cc = 0; cc < 4; ++cc){
      const int c = wid * 4 + cc;
      const int row = c * 8 + ldrow;
      gload_lds16(&A[(size_t)(m0 + row) * Kdim + k0 + ldcol], &sA[c*8][0]);
      gload_lds16(&B[(size_t)(n0 + row) * Kdim + k0 + ldcol], &sB[c*8][0]);
    }
    __syncthreads();   // drains vmcnt before barrier
#pragma unroll
    for (int kk = 0; kk < 64; kk += 32){
      half8 fa[4], fb[4];
#pragma unroll
      for (int t = 0; t < 4; ++t){
        fa[t] = *reinterpret_cast<const half8*>(&sA[wr + t*16 + lr][kk + lc*8]);
        fb[t] = *reinterpret_cast<const half8*>(&sB[wc + t*16 + lr][kk + lc*8]);
      }
#pragma unroll
      for (int mt = 0; mt < 4; ++mt)
#pragma unroll
        for (int nt = 0; nt < 4; ++nt)
          acc[mt][nt] = MFMA16(fa[mt], fb[nt], acc[mt][nt]);
    }
    __syncthreads();
  }
  // epilogue: C/D layout col=lane&15, row=(lane>>4)*4+reg  [m89]
#pragma unroll
  for (int mt = 0; mt < 4; ++mt)
#pragma unroll
    for (int nt = 0; nt < 4; ++nt)
#pragma unroll
      for (int r = 0; r < 4; ++r){
        const int m = m0 + wr + mt*16 + lc*4 + r;
        const int n = n0 + wc + nt*16 + lr;
        float v = acc[mt][nt][r];
        if (EPI == 0){
          Cout[(size_t)m * Ndim + n] = v;
        } else {
          const int t = n >> 10, rem = n & 1023, hh = rem >> 6, d = rem & 63;
          const int b = m >> 11, s = m & 2047;
          const int bh = b * H_NUM + hh;
          if (t == 0) v *= (0.125f * LOG2E);  // fold 1/sqrt(64) and log2(e) into Q
          size_t o;
          if (t == 2)  o = ((size_t)bh * D_DIM + d) * S_LEN + s;   // V transposed
          else         o = ((size_t)bh * S_LEN + s) * D_DIM + d;
          _Float16* ph = (t == 0) ? qh : (t == 1) ? kh : vh;
          ph[o] = (_Float16)v;
        }
      }
}

// ---------------- flash attention with ghost softmax (all fp16) ----------------
// WG: (pair, bh). Each block does q-tiles (31-p) then (p): exactly 33 KV-iters.
// 4 waves x 16 q-rows. Double-buffered K/V LDS, 1 barrier/iter, reg prefetch,
// DPP (VALU-pipe) reductions, log2-domain softmax with defer-max.
__global__ __launch_bounds__(256, 2) void attn_kernel(
    const _Float16* __restrict__ Qh, const _Float16* __restrict__ Kh,
    const _Float16* __restrict__ Vth, _Float16* __restrict__ Ao)
{
  constexpr int LDV = 72;
  __shared__ __align__(16) _Float16 sKh[2][64][LDV], sVh[2][64][LDV];
  __shared__ __align__(16) _Float16 sP[4][16][LDV];            // per-wave P tile [q][token]
  const int tid = threadIdx.x, wid = tid >> 6, lane = tid & 63;
  const int pr = blockIdx.x;            // 0..15
  const int bh = blockIdx.y;
  const int lr = lane & 15, lc = lane >> 4;
  const size_t base = (size_t)bh * S_LEN * D_DIM;

  // staging geometry (two 16B chunks per thread per array)
  const int i1 = tid + 256;
  const int r0 = tid >> 3, c80 = (tid & 7) * 8;
  const int r1 = i1 >> 3,  c81 = (i1 & 7) * 8;

  int4 rK0, rK1, rV0, rV1;
  auto issue = [&](int t){
    const int kv0 = t * 64;
    rK0 = *reinterpret_cast<const int4*>(&Kh[base + (size_t)(kv0 + r0) * D_DIM + c80]);
    rK1 = *reinterpret_cast<const int4*>(&Kh[base + (size_t)(kv0 + r1) * D_DIM + c81]);
    rV0 = *reinterpret_cast<const int4*>(&Vth[base + (size_t)r0 * S_LEN + kv0 + c80]);
    rV1 = *reinterpret_cast<const int4*>(&Vth[base + (size_t)r1 * S_LEN + kv0 + c81]);
  };
  auto store = [&](int buf){
    *reinterpret_cast<int4*>(&sKh[buf][r0][c80]) = rK0;
    *reinterpret_cast<int4*>(&sKh[buf][r1][c81]) = rK1;
    *reinterpret_cast<int4*>(&sVh[buf][r0][c80]) = rV0;
    *reinterpret_cast<int4*>(&sVh[buf][r1][c81]) = rV1;
  };

  const int b = bh >> 4, hh = bh & 15;

  for (int half = 0; half < 2; ++half){
    const int qt = half ? pr : (31 - pr);
    const int q0 = qt * 64;
    const int nT = qt + 1;

    // Q fragments (A-operand), hoisted; Q already scaled by log2e/8
    half8 fq[2];
    {
      const int qrow = q0 + wid*16 + lr;
#pragma unroll
      for (int kc = 0; kc < 2; ++kc)
        fq[kc] = *reinterpret_cast<const half8*>(&Qh[base + (size_t)qrow * 64 + kc*32 + lc*8]);
    }

    f32x4 acc[4] = {};
    float mrow[4], lrow[4], tmrow[4];
#pragma unroll
    for (int r = 0; r < 4; ++r){ mrow[r] = -1e30f; lrow[r] = 0.f; tmrow[r] = -1e30f; }

    // prologue: fill buf0 with tile 0, prefetch tile 1 into regs
    issue(0);
    __syncthreads();          // prev half's LDS reads complete
    store(0);
    if (nT > 1) issue(1);
    __syncthreads();

    int cur = 0;
    for (int t = 0; t < nT; ++t){
      // regs hold tile t+1 -> write to back buffer, then prefetch t+2
      if (t + 1 < nT){
        store(cur ^ 1);
        if (t + 2 < nT) issue(t + 2);
      }

      // scores: QK^T from LDS (log2 domain), single-term fp16
      f32x4 sc[4];
#pragma unroll
      for (int nt = 0; nt < 4; ++nt){
        f32x4 z = {};
#pragma unroll
        for (int kc = 0; kc < 2; ++kc){
          const half8 fk = *reinterpret_cast<const half8*>(&sKh[cur][nt*16 + lr][kc*32 + lc*8]);
          z = MFMA16(fq[kc], fk, z);
        }
        sc[nt] = z;
      }

      if (t == qt){   // diagonal block: mask k > q
#pragma unroll
        for (int nt = 0; nt < 4; ++nt)
#pragma unroll
          for (int r = 0; r < 4; ++r)
            if (nt*16 + lr > wid*16 + lc*4 + r) sc[nt][r] = -1e30f;
      }

      // online softmax, defer-max (THR=8 in log2 units); DPP reductions
      float mx4[4];
      int need = 0;
#pragma unroll
      for (int r = 0; r < 4; ++r){
        float mx = fmaxf(fmaxf(sc[0][r], sc[1][r]), fmaxf(sc[2][r], sc[3][r]));
        mx = rmax16(mx);
        mx4[r] = mx;
        tmrow[r] = fmaxf(tmrow[r], mx);
        need |= (mx > mrow[r] + 8.0f) ? 1 : 0;
      }
      if (__any(need)){
#pragma unroll
        for (int r = 0; r < 4; ++r){
          const float mn = fmaxf(mrow[r], mx4[r]);
          const float scale = exp2_fast(mrow[r] - mn);
          lrow[r] *= scale;
          mrow[r] = mn;
#pragma unroll
          for (int dt = 0; dt < 4; ++dt) acc[dt][r] *= scale;
        }
      }
#pragma unroll
      for (int r = 0; r < 4; ++r){
        float sum = 0.f;
#pragma unroll
        for (int nt = 0; nt < 4; ++nt){
          const float pv = exp2_fast(sc[nt][r] - mrow[r]);
          sc[nt][r] = pv;
          sum += pv;
        }
        lrow[r] += rsum16(sum);
      }

      // P (fp16) -> per-wave LDS tile, then read back in A-frag layout
#pragma unroll
      for (int nt = 0; nt < 4; ++nt)
#pragma unroll
        for (int r = 0; r < 4; ++r)
          sP[wid][lc*4 + r][nt*16 + lr] = (_Float16)sc[nt][r];

      half8 pa[2];
#pragma unroll
      for (int kc = 0; kc < 2; ++kc)
        pa[kc] = *reinterpret_cast<const half8*>(&sP[wid][lr][kc*32 + lc*8]);
#pragma unroll
      for (int dt = 0; dt < 4; ++dt){
#pragma unroll
        for (int kc = 0; kc < 2; ++kc){
          const half8 fv = *reinterpret_cast<const half8*>(&sVh[cur][dt*16 + lr][kc*32 + lc*8]);
          acc[dt] = MFMA16(pa[kc], fv, acc[dt]);
        }
      }

      __syncthreads();   // back buffer written by all, front buffer reads done
      cur ^= 1;
    }

    // finalize: ghost term = 2^(truemax - m); write A fp16 in (B,S,H*D)
#pragma unroll
    for (int dt = 0; dt < 4; ++dt)
#pragma unroll
      for (int r = 0; r < 4; ++r){
        const float denom = lrow[r] + exp2_fast(tmrow[r] - mrow[r]);
        const float o = acc[dt][r] / denom;
        const int q = q0 + wid*16 + lc*4 + r;
        const int d = dt*16 + lr;
        Ao[((size_t)(b*S_LEN + q)) * E_DIM + hh*D_DIM + d] = (_Float16)o;
      }
  }
}

// ---------------- launch ----------------
extern "C" void kernel_launch(void* const* d_in, const int* in_sizes, int n_in,
                              void* d_out, int out_size, void* d_ws, size_t ws_size,
                              hipStream_t stream){
  const float* X    = (const float*)d_in[0];
  const float* Wqkv = (const float*)d_in[1];
  const float* Wo   = (const float*)d_in[2];
  float* out = (float*)d_out;

  _Float16* w = (_Float16*)d_ws;
  size_t off = 0;
  auto alloc = [&](size_t n){ _Float16* p = w + off; off += n; return p; };
  const size_t ME   = (size_t)M_ROWS * E_DIM;
  const size_t WQ   = (size_t)N3 * E_DIM;
  const size_t WOsz = (size_t)E_DIM * E_DIM;
  const size_t QK   = (size_t)NBH * S_LEN * D_DIM;
  _Float16 *Xh = alloc(ME);
  _Float16 *Wqh = alloc(WQ);
  _Float16 *Woh = alloc(WOsz);
  _Float16 *Qh = alloc(QK), *Kh = alloc(QK), *Vth = alloc(QK);
  _Float16 *Ahalf = alloc(ME);

  cast_x_kernel<<<(int)(ME/4/256), 256, 0, stream>>>(X, Xh, (int)(ME/4));
  transpose_half<<<dim3(N3/32, E_DIM/32), 256, 0, stream>>>(Wqkv, Wqh, E_DIM, N3);
  transpose_half<<<dim3(E_DIM/32, E_DIM/32), 256, 0, stream>>>(Wo, Woh, E_DIM, E_DIM);

  gemm97<1><<<dim3(N3/128, M_ROWS/128), 256, 0, stream>>>(
      Xh, Wqh, E_DIM, N3, nullptr, Qh, Kh, Vth);

  attn_kernel<<<dim3(16, NBH), 256, 0, stream>>>(Qh, Kh, Vth, Ahalf);

  gemm97<0><<<dim3(E_DIM/128, M_ROWS/128), 256, 0, stream>>>(
      Ahalf, Woh, E_DIM, E_DIM, out, nullptr, nullptr, nullptr);
}

// Round 7
// 133.161 us; speedup vs baseline: 2.8933x; 1.0683x over previous
//
#include <hip/hip_runtime.h>

typedef float    f32x4  __attribute__((ext_vector_type(4)));
typedef _Float16 half8  __attribute__((ext_vector_type(8)));
typedef _Float16 half4v __attribute__((ext_vector_type(4)));
typedef _Float16 half2v __attribute__((ext_vector_type(2)));

#define MFMA16(a,b,c) __builtin_amdgcn_mfma_f32_16x16x32_f16(a,b,c,0,0,0)

__device__ __forceinline__ float exp2_fast(float x){
  float y; asm("v_exp_f32 %0, %1" : "=v"(y) : "v"(x)); return y;
}
// async global->LDS, 16B per lane; LDS dest is wave-uniform base + lane*16
__device__ __forceinline__ void gload_lds16(const _Float16* g, _Float16* l){
  __builtin_amdgcn_global_load_lds(
      (const __attribute__((address_space(1))) unsigned int*)(g),
      (__attribute__((address_space(3))) unsigned int*)(l),
      16, 0, 0);
}

#define S_LEN 2048
#define E_DIM 1024
#define H_NUM 16
#define D_DIM 64
#define NBH   32
#define M_ROWS 4096
#define N3    3072
#define LOG2E 1.44269504089f

// ---------------- prep: fp32 -> fp16 cast ----------------
__global__ void cast_x_kernel(const float* __restrict__ in,
                              _Float16* __restrict__ hi, int n4){
  int i = blockIdx.x * 256 + threadIdx.x;
  if (i >= n4) return;
  const float4 v = reinterpret_cast<const float4*>(in)[i];
  half4v h;
  h[0] = (_Float16)v.x; h[1] = (_Float16)v.y;
  h[2] = (_Float16)v.z; h[3] = (_Float16)v.w;
  *reinterpret_cast<half4v*>(&hi[i*4]) = h;
}

// out[n][k] = in[k][n], single fp16. in is R x C, out is C x R.
__global__ void transpose_half(const float* __restrict__ in,
                               _Float16* __restrict__ hi, int R, int C){
  __shared__ float tile[32][33];
  int bx = blockIdx.x * 32, by = blockIdx.y * 32;
  int tx = threadIdx.x & 31, ty = threadIdx.x >> 5;   // 256 threads = 32x8
#pragma unroll
  for (int i = ty; i < 32; i += 8)
    tile[i][tx] = in[(size_t)(by + i) * C + bx + tx];
  __syncthreads();
#pragma unroll
  for (int i = ty; i < 32; i += 8)
    hi[(size_t)(bx + i) * R + by + tx] = (_Float16)tile[tx][i];
}

// ---------------- fp16 GEMM (m97 structure): C = A @ B^T(rowmajor N x K) ----
template<int EPI>
__global__ __launch_bounds__(256, 3) void gemm97(
    const _Float16* __restrict__ A, const _Float16* __restrict__ B,
    int Kdim, int Ndim, float* __restrict__ Cout,
    _Float16* __restrict__ qh, _Float16* __restrict__ kh, _Float16* __restrict__ vh)
{
  __shared__ __align__(16) _Float16 sA[128][64], sB[128][64];
  const int tid = threadIdx.x;
  const int m0 = blockIdx.y * 128, n0 = blockIdx.x * 128;
  const int wid = tid >> 6, lane = tid & 63;
  const int wr = (wid >> 1) * 64, wc = (wid & 1) * 64;
  const int lr = lane & 15, lc = lane >> 4;
  const int ldrow = lane >> 3, ldcol = (lane & 7) * 8;

  f32x4 acc[4][4] = {};
  const int nK = Kdim >> 6;
  for (int ks = 0; ks < nK; ++ks){
    const int k0 = ks << 6;
#pragma unroll
    for (int cc = 0; cc < 4; ++cc){
      const int c = wid * 4 + cc;
      const int row = c * 8 + ldrow;
      gload_lds16(&A[(size_t)(m0 + row) * Kdim + k0 + ldcol], &sA[c*8][0]);
      gload_lds16(&B[(size_t)(n0 + row) * Kdim + k0 + ldcol], &sB[c*8][0]);
    }
    __syncthreads();
#pragma unroll
    for (int kk = 0; kk < 64; kk += 32){
      half8 fa[4], fb[4];
#pragma unroll
      for (int t = 0; t < 4; ++t){
        fa[t] = *reinterpret_cast<const half8*>(&sA[wr + t*16 + lr][kk + lc*8]);
        fb[t] = *reinterpret_cast<const half8*>(&sB[wc + t*16 + lr][kk + lc*8]);
      }
#pragma unroll
      for (int mt = 0; mt < 4; ++mt)
#pragma unroll
        for (int nt = 0; nt < 4; ++nt)
          acc[mt][nt] = MFMA16(fa[mt], fb[nt], acc[mt][nt]);
    }
    __syncthreads();
  }
#pragma unroll
  for (int mt = 0; mt < 4; ++mt)
#pragma unroll
    for (int nt = 0; nt < 4; ++nt)
#pragma unroll
      for (int r = 0; r < 4; ++r){
        const int m = m0 + wr + mt*16 + lc*4 + r;
        const int n = n0 + wc + nt*16 + lr;
        float v = acc[mt][nt][r];
        if (EPI == 0){
          Cout[(size_t)m * Ndim + n] = v;
        } else {
          const int t = n >> 10, rem = n & 1023, hh = rem >> 6, d = rem & 63;
          const int b = m >> 11, s = m & 2047;
          const int bh = b * H_NUM + hh;
          if (t == 0) v *= (0.125f * LOG2E);  // fold 1/sqrt(64) and log2(e) into Q
          size_t o;
          if (t == 2)  o = ((size_t)bh * D_DIM + d) * S_LEN + s;   // V transposed
          else         o = ((size_t)bh * S_LEN + s) * D_DIM + d;
          _Float16* ph = (t == 0) ? qh : (t == 1) ? kh : vh;
          ph[o] = (_Float16)v;
        }
      }
}

// ---------------- flash attention, transposed-QK in-register softmax ----------
// WG: (pair, bh). Each block does q-tiles (31-p) then (p): exactly 33 KV-iters.
// 4 waves x 16 q-rows. ST = MFMA(K,Q) puts col=q(lane&15), rows=k. K/V staged
// via global_load_lds into linear [64][64] LDS with XOR-swizzled global source.
__global__ __launch_bounds__(256, 2) void attn_kernel(
    const _Float16* __restrict__ Qh, const _Float16* __restrict__ Kh,
    const _Float16* __restrict__ Vth, _Float16* __restrict__ Ao)
{
  __shared__ __align__(16) _Float16 sK[2][64][64], sV[2][64][64];
  __shared__ __align__(16) _Float16 sP[4][16][72];   // per-wave P [q][k], pad 72
  const int tid = threadIdx.x, wid = tid >> 6, lane = tid & 63;
  const int pr = blockIdx.x;            // 0..15
  const int bh = blockIdx.y;
  const int lr = lane & 15, lc = lane >> 4;
  const int swz = (lr & 7) << 4;        // byte XOR for swizzled fragment reads
  const size_t base = (size_t)bh * S_LEN * D_DIM;

  // staging geometry: wave w stages chunks {2w,2w+1} (8 rows each) of K and V
  const int lrow = lane >> 3;                       // 0..7
  const int cswz = ((lane & 7) ^ lrow) * 8;         // inverse-swizzled source col (halfs)

  auto stage = [&](int t, int b){
    const int kv0 = t * 64;
#pragma unroll
    for (int cc = 0; cc < 2; ++cc){
      const int c = wid * 2 + cc;
      const int row = c * 8 + lrow;
      gload_lds16(&Kh[base + (size_t)(kv0 + row) * D_DIM + cswz], &sK[b][c*8][0]);
      gload_lds16(&Vth[base + (size_t)row * S_LEN + kv0 + cswz], &sV[b][c*8][0]);
    }
  };

  const int b = bh >> 4, hh = bh & 15;

  for (int half = 0; half < 2; ++half){
    const int qt = half ? pr : (31 - pr);
    const int q0 = qt * 64;
    const int nT = qt + 1;

    // Q fragments (B-operand now), hoisted; Q already scaled by log2e/8
    half8 fq[2];
    {
      const int qrow = q0 + wid*16 + lr;
#pragma unroll
      for (int kc = 0; kc < 2; ++kc)
        fq[kc] = *reinterpret_cast<const half8*>(&Qh[base + (size_t)qrow * 64 + kc*32 + lc*8]);
    }

    f32x4 acc[4] = {};
    float m = -1e30f, l = 0.f, tm = -1e30f;   // per-lane stats for q = lr

    stage(0, 0);
    __syncthreads();

    int cur = 0;
    for (int t = 0; t < nT; ++t){
      if (t + 1 < nT) stage(t + 1, cur ^ 1);   // async loads hide under compute

      // ST = K·Q^T: lane holds q=lr (col), k = nt*16 + lc*4 + r (row)
      const char* kb = (const char*)&sK[cur][0][0];
      f32x4 sc[4];
#pragma unroll
      for (int nt = 0; nt < 4; ++nt){
        f32x4 z = {};
#pragma unroll
        for (int kc = 0; kc < 2; ++kc){
          const half8 fk = *reinterpret_cast<const half8*>(
              kb + (nt*16 + lr)*128 + ((kc*64 + lc*16) ^ swz));
          z = MFMA16(fk, fq[kc], z);
        }
        sc[nt] = z;
      }

      if (t == qt){   // diagonal: mask k > q
#pragma unroll
        for (int nt = 0; nt < 4; ++nt)
#pragma unroll
          for (int r = 0; r < 4; ++r)
            if (nt*16 + lc*4 + r > wid*16 + lr) sc[nt][r] = -1e30f;
      }

      // in-lane max over 16 + 2 cross-lane hops (lanes lr, lr+16, lr+32, lr+48)
      f32x4 a;
#pragma unroll
      for (int j = 0; j < 4; ++j)
        a[j] = fmaxf(fmaxf(sc[0][j], sc[1][j]), fmaxf(sc[2][j], sc[3][j]));
      float mx = fmaxf(fmaxf(a[0], a[1]), fmaxf(a[2], a[3]));
      mx = fmaxf(mx, __shfl_xor(mx, 16));
      mx = fmaxf(mx, __shfl_xor(mx, 32));
      tm = fmaxf(tm, mx);

      if (__any(mx > m + 8.0f)){   // defer-max THR=8 (log2 units)
        const float mn = fmaxf(m, mx);
        const float s = exp2_fast(m - mn);
        l *= s; m = mn;
        float rs[4];
#pragma unroll
        for (int r = 0; r < 4; ++r)
          rs[r] = __shfl(s, (lc << 4) | (lc*4 + r), 64);
#pragma unroll
        for (int dt = 0; dt < 4; ++dt)
#pragma unroll
          for (int r = 0; r < 4; ++r) acc[dt][r] *= rs[r];
      }

      // P = exp2(sc - m); in-lane sum + 2 hops
      f32x4 ssum = {};
#pragma unroll
      for (int nt = 0; nt < 4; ++nt){
#pragma unroll
        for (int r = 0; r < 4; ++r) sc[nt][r] = exp2_fast(sc[nt][r] - m);
        ssum += sc[nt];
      }
      float s1 = (ssum[0] + ssum[1]) + (ssum[2] + ssum[3]);
      s1 += __shfl_xor(s1, 16);
      s1 += __shfl_xor(s1, 32);
      l += s1;

      // pack P pairs -> 4 x ds_write_b64 of consecutive k (k = 16nt + 4lc + 0..3)
#pragma unroll
      for (int nt = 0; nt < 4; ++nt){
        int2 pk;
        pk.x = __builtin_bit_cast(int, __builtin_amdgcn_cvt_pkrtz(sc[nt][0], sc[nt][1]));
        pk.y = __builtin_bit_cast(int, __builtin_amdgcn_cvt_pkrtz(sc[nt][2], sc[nt][3]));
        *reinterpret_cast<int2*>(&sP[wid][lr][nt*16 + lc*4]) = pk;
      }

      // PV: pa is the A-fragment (row q=lr, k = kc*32 + lc*8 + j)
      const half8 pa0 = *reinterpret_cast<const half8*>(&sP[wid][lr][lc*8]);
      const half8 pa1 = *reinterpret_cast<const half8*>(&sP[wid][lr][32 + lc*8]);
      const char* vb = (const char*)&sV[cur][0][0];
#pragma unroll
      for (int dt = 0; dt < 4; ++dt){
#pragma unroll
        for (int kc = 0; kc < 2; ++kc){
          const half8 fv = *reinterpret_cast<const half8*>(
              vb + (dt*16 + lr)*128 + ((kc*64 + lc*16) ^ swz));
          acc[dt] = MFMA16(kc ? pa1 : pa0, fv, acc[dt]);
        }
      }

      __syncthreads();   // drains next-tile gloads; guards buffer swap
      cur ^= 1;
    }

    // finalize: ghost term = 2^(truemax - m); denom broadcast per q-row
    const float den = l + exp2_fast(tm - m);
    float rden[4];
#pragma unroll
    for (int r = 0; r < 4; ++r)
      rden[r] = __shfl(den, (lc << 4) | (lc*4 + r), 64);
#pragma unroll
    for (int dt = 0; dt < 4; ++dt)
#pragma unroll
      for (int r = 0; r < 4; ++r){
        const float o = acc[dt][r] / rden[r];
        const int q = q0 + wid*16 + lc*4 + r;
        const int d = dt*16 + lr;
        Ao[((size_t)(b*S_LEN + q)) * E_DIM + hh*D_DIM + d] = (_Float16)o;
      }
  }
}

// ---------------- launch ----------------
extern "C" void kernel_launch(void* const* d_in, const int* in_sizes, int n_in,
                              void* d_out, int out_size, void* d_ws, size_t ws_size,
                              hipStream_t stream){
  const float* X    = (const float*)d_in[0];
  const float* Wqkv = (const float*)d_in[1];
  const float* Wo   = (const float*)d_in[2];
  float* out = (float*)d_out;

  _Float16* w = (_Float16*)d_ws;
  size_t off = 0;
  auto alloc = [&](size_t n){ _Float16* p = w + off; off += n; return p; };
  const size_t ME   = (size_t)M_ROWS * E_DIM;
  const size_t WQ   = (size_t)N3 * E_DIM;
  const size_t WOsz = (size_t)E_DIM * E_DIM;
  const size_t QK   = (size_t)NBH * S_LEN * D_DIM;
  _Float16 *Xh = alloc(ME);
  _Float16 *Wqh = alloc(WQ);
  _Float16 *Woh = alloc(WOsz);
  _Float16 *Qh = alloc(QK), *Kh = alloc(QK), *Vth = alloc(QK);
  _Float16 *Ahalf = alloc(ME);

  cast_x_kernel<<<(int)(ME/4/256), 256, 0, stream>>>(X, Xh, (int)(ME/4));
  transpose_half<<<dim3(N3/32, E_DIM/32), 256, 0, stream>>>(Wqkv, Wqh, E_DIM, N3);
  transpose_half<<<dim3(E_DIM/32, E_DIM/32), 256, 0, stream>>>(Wo, Woh, E_DIM, E_DIM);

  gemm97<1><<<dim3(N3/128, M_ROWS/128), 256, 0, stream>>>(
      Xh, Wqh, E_DIM, N3, nullptr, Qh, Kh, Vth);

  attn_kernel<<<dim3(16, NBH), 256, 0, stream>>>(Qh, Kh, Vth, Ahalf);

  gemm97<0><<<dim3(E_DIM/128, M_ROWS/128), 256, 0, stream>>>(
      Ahalf, Woh, E_DIM, E_DIM, out, nullptr, nullptr, nullptr);
}

// Round 8
// 125.934 us; speedup vs baseline: 3.0594x; 1.0574x over previous
//
#include <hip/hip_runtime.h>

typedef float    f32x4  __attribute__((ext_vector_type(4)));
typedef _Float16 half8  __attribute__((ext_vector_type(8)));
typedef _Float16 half4v __attribute__((ext_vector_type(4)));

#define MFMA16(a,b,c) __builtin_amdgcn_mfma_f32_16x16x32_f16(a,b,c,0,0,0)

__device__ __forceinline__ float exp2_fast(float x){
  float y; asm("v_exp_f32 %0, %1" : "=v"(y) : "v"(x)); return y;
}
// async global->LDS, 16B per lane; LDS dest is wave-uniform base + lane*16
__device__ __forceinline__ void gload_lds16(const _Float16* g, _Float16* l){
  __builtin_amdgcn_global_load_lds(
      (const __attribute__((address_space(1))) unsigned int*)(g),
      (__attribute__((address_space(3))) unsigned int*)(l),
      16, 0, 0);
}

#define S_LEN 2048
#define E_DIM 1024
#define H_NUM 16
#define D_DIM 64
#define NBH   32
#define M_ROWS 4096
#define N3    3072
#define LOG2E 1.44269504089f

// ---------------- prep: fp32 -> fp16 cast ----------------
__global__ void cast_x_kernel(const float* __restrict__ in,
                              _Float16* __restrict__ hi, int n4){
  int i = blockIdx.x * 256 + threadIdx.x;
  if (i >= n4) return;
  const float4 v = reinterpret_cast<const float4*>(in)[i];
  half4v h;
  h[0] = (_Float16)v.x; h[1] = (_Float16)v.y;
  h[2] = (_Float16)v.z; h[3] = (_Float16)v.w;
  *reinterpret_cast<half4v*>(&hi[i*4]) = h;
}

// out[n][k] = in[k][n], single fp16. in is R x C, out is C x R.
__global__ void transpose_half(const float* __restrict__ in,
                               _Float16* __restrict__ hi, int R, int C){
  __shared__ float tile[32][33];
  int bx = blockIdx.x * 32, by = blockIdx.y * 32;
  int tx = threadIdx.x & 31, ty = threadIdx.x >> 5;   // 256 threads = 32x8
#pragma unroll
  for (int i = ty; i < 32; i += 8)
    tile[i][tx] = in[(size_t)(by + i) * C + bx + tx];
  __syncthreads();
#pragma unroll
  for (int i = ty; i < 32; i += 8)
    hi[(size_t)(bx + i) * R + by + tx] = (_Float16)tile[tx][i];
}

// ---------------- fp16 GEMM (m97 structure): C = A @ B^T(rowmajor N x K) ----
template<int EPI>
__global__ __launch_bounds__(256, 3) void gemm97(
    const _Float16* __restrict__ A, const _Float16* __restrict__ B,
    int Kdim, int Ndim, float* __restrict__ Cout,
    _Float16* __restrict__ qh, _Float16* __restrict__ kh, _Float16* __restrict__ vh)
{
  __shared__ __align__(16) _Float16 sA[128][64], sB[128][64];
  const int tid = threadIdx.x;
  const int m0 = blockIdx.y * 128, n0 = blockIdx.x * 128;
  const int wid = tid >> 6, lane = tid & 63;
  const int wr = (wid >> 1) * 64, wc = (wid & 1) * 64;
  const int lr = lane & 15, lc = lane >> 4;
  const int ldrow = lane >> 3, ldcol = (lane & 7) * 8;

  f32x4 acc[4][4] = {};
  const int nK = Kdim >> 6;
  for (int ks = 0; ks < nK; ++ks){
    const int k0 = ks << 6;
#pragma unroll
    for (int cc = 0; cc < 4; ++cc){
      const int c = wid * 4 + cc;
      const int row = c * 8 + ldrow;
      gload_lds16(&A[(size_t)(m0 + row) * Kdim + k0 + ldcol], &sA[c*8][0]);
      gload_lds16(&B[(size_t)(n0 + row) * Kdim + k0 + ldcol], &sB[c*8][0]);
    }
    __syncthreads();
#pragma unroll
    for (int kk = 0; kk < 64; kk += 32){
      half8 fa[4], fb[4];
#pragma unroll
      for (int t = 0; t < 4; ++t){
        fa[t] = *reinterpret_cast<const half8*>(&sA[wr + t*16 + lr][kk + lc*8]);
        fb[t] = *reinterpret_cast<const half8*>(&sB[wc + t*16 + lr][kk + lc*8]);
      }
#pragma unroll
      for (int mt = 0; mt < 4; ++mt)
#pragma unroll
        for (int nt = 0; nt < 4; ++nt)
          acc[mt][nt] = MFMA16(fa[mt], fb[nt], acc[mt][nt]);
    }
    __syncthreads();
  }
#pragma unroll
  for (int mt = 0; mt < 4; ++mt)
#pragma unroll
    for (int nt = 0; nt < 4; ++nt)
#pragma unroll
      for (int r = 0; r < 4; ++r){
        const int m = m0 + wr + mt*16 + lc*4 + r;
        const int n = n0 + wc + nt*16 + lr;
        float v = acc[mt][nt][r];
        if (EPI == 0){
          Cout[(size_t)m * Ndim + n] = v;
        } else {
          const int t = n >> 10, rem = n & 1023, hh = rem >> 6, d = rem & 63;
          const int b = m >> 11, s = m & 2047;
          const int bh = b * H_NUM + hh;
          if (t == 0) v *= (0.125f * LOG2E);  // fold 1/sqrt(64) and log2(e) into Q
          size_t o;
          if (t == 2)  o = ((size_t)bh * D_DIM + d) * S_LEN + s;   // V transposed
          else         o = ((size_t)bh * S_LEN + s) * D_DIM + d;
          _Float16* ph = (t == 0) ? qh : (t == 1) ? kh : vh;
          ph[o] = (_Float16)v;
        }
      }
}

// ---------------- flash attention, transposed-QK in-register softmax ----------
// Grid 32x32, one q-tile per block, 3 blocks/CU. XCD-aware remap: each XCD
// serves bh in {xcd, xcd+8, xcd+16, xcd+24} (2MB K/V -> L2-resident), qt
// descending so heavy blocks dispatch first.
__global__ __launch_bounds__(256, 3) void attn_kernel(
    const _Float16* __restrict__ Qh, const _Float16* __restrict__ Kh,
    const _Float16* __restrict__ Vth, _Float16* __restrict__ Ao)
{
  __shared__ __align__(16) _Float16 sK[2][64][64], sV[2][64][64];
  __shared__ __align__(16) _Float16 sP[4][16][72];   // per-wave P [q][k], pad 72
  const int tid = threadIdx.x, wid = tid >> 6, lane = tid & 63;
  const int id  = blockIdx.x + 32 * blockIdx.y;
  const int xcd = id & 7, seq = id >> 3;
  const int bh  = xcd + 8 * (seq & 3);
  const int qt  = 31 - (seq >> 2);
  const int q0 = qt * 64;
  const int nT = qt + 1;
  const int lr = lane & 15, lc = lane >> 4;
  const int swz = (lr & 7) << 4;        // byte XOR for swizzled fragment reads
  const size_t base = (size_t)bh * S_LEN * D_DIM;

  // staging geometry: wave w stages chunks {2w,2w+1} (8 rows each) of K and V
  const int lrow = lane >> 3;                       // 0..7
  const int cswz = ((lane & 7) ^ lrow) * 8;         // inverse-swizzled source col (halfs)

  auto stage = [&](int t, int b){
    const int kv0 = t * 64;
#pragma unroll
    for (int cc = 0; cc < 2; ++cc){
      const int c = wid * 2 + cc;
      const int row = c * 8 + lrow;
      gload_lds16(&Kh[base + (size_t)(kv0 + row) * D_DIM + cswz], &sK[b][c*8][0]);
      gload_lds16(&Vth[base + (size_t)row * S_LEN + kv0 + cswz], &sV[b][c*8][0]);
    }
  };

  const int b = bh >> 4, hh = bh & 15;

  // Q fragments (B-operand), hoisted; Q already scaled by log2e/8
  half8 fq[2];
  {
    const int qrow = q0 + wid*16 + lr;
#pragma unroll
    for (int kc = 0; kc < 2; ++kc)
      fq[kc] = *reinterpret_cast<const half8*>(&Qh[base + (size_t)qrow * 64 + kc*32 + lc*8]);
  }

  f32x4 acc[4] = {};
  float m = -1e30f, l = 0.f, tm = -1e30f;   // per-lane stats for q = lr

  stage(0, 0);
  __syncthreads();

  int cur = 0;
  for (int t = 0; t < nT; ++t){
    if (t + 1 < nT) stage(t + 1, cur ^ 1);   // async loads hide under compute

    // ST = K·Q^T: lane holds q=lr (col), k = nt*16 + lc*4 + r (row)
    const char* kb = (const char*)&sK[cur][0][0];
    f32x4 sc[4];
#pragma unroll
    for (int nt = 0; nt < 4; ++nt){
      f32x4 z = {};
#pragma unroll
      for (int kc = 0; kc < 2; ++kc){
        const half8 fk = *reinterpret_cast<const half8*>(
            kb + (nt*16 + lr)*128 + ((kc*64 + lc*16) ^ swz));
        z = MFMA16(fk, fq[kc], z);
      }
      sc[nt] = z;
    }

    if (t == qt){   // diagonal: mask k > q
#pragma unroll
      for (int nt = 0; nt < 4; ++nt)
#pragma unroll
        for (int r = 0; r < 4; ++r)
          if (nt*16 + lc*4 + r > wid*16 + lr) sc[nt][r] = -1e30f;
    }

    // in-lane max over 16 + 2 cross-lane hops (lanes lr, lr+16, lr+32, lr+48)
    f32x4 a;
#pragma unroll
    for (int j = 0; j < 4; ++j)
      a[j] = fmaxf(fmaxf(sc[0][j], sc[1][j]), fmaxf(sc[2][j], sc[3][j]));
    float mx = fmaxf(fmaxf(a[0], a[1]), fmaxf(a[2], a[3]));
    mx = fmaxf(mx, __shfl_xor(mx, 16));
    mx = fmaxf(mx, __shfl_xor(mx, 32));
    tm = fmaxf(tm, mx);

    if (__any(mx > m + 8.0f)){   // defer-max THR=8 (log2 units)
      const float mn = fmaxf(m, mx);
      const float s = exp2_fast(m - mn);
      l *= s; m = mn;
      float rs[4];
#pragma unroll
      for (int r = 0; r < 4; ++r)
        rs[r] = __shfl(s, (lc << 4) | (lc*4 + r), 64);
#pragma unroll
      for (int dt = 0; dt < 4; ++dt)
#pragma unroll
        for (int r = 0; r < 4; ++r) acc[dt][r] *= rs[r];
    }

    // P = exp2(sc - m); in-lane sum + 2 hops
    f32x4 ssum = {};
#pragma unroll
    for (int nt = 0; nt < 4; ++nt){
#pragma unroll
      for (int r = 0; r < 4; ++r) sc[nt][r] = exp2_fast(sc[nt][r] - m);
      ssum += sc[nt];
    }
    float s1 = (ssum[0] + ssum[1]) + (ssum[2] + ssum[3]);
    s1 += __shfl_xor(s1, 16);
    s1 += __shfl_xor(s1, 32);
    l += s1;

    // pack P pairs -> 4 x ds_write_b64 of consecutive k (k = 16nt + 4lc + 0..3)
#pragma unroll
    for (int nt = 0; nt < 4; ++nt){
      int2 pk;
      pk.x = __builtin_bit_cast(int, __builtin_amdgcn_cvt_pkrtz(sc[nt][0], sc[nt][1]));
      pk.y = __builtin_bit_cast(int, __builtin_amdgcn_cvt_pkrtz(sc[nt][2], sc[nt][3]));
      *reinterpret_cast<int2*>(&sP[wid][lr][nt*16 + lc*4]) = pk;
    }

    // PV: pa is the A-fragment (row q=lr, k = kc*32 + lc*8 + j)
    const half8 pa0 = *reinterpret_cast<const half8*>(&sP[wid][lr][lc*8]);
    const half8 pa1 = *reinterpret_cast<const half8*>(&sP[wid][lr][32 + lc*8]);
    const char* vb = (const char*)&sV[cur][0][0];
#pragma unroll
    for (int dt = 0; dt < 4; ++dt){
#pragma unroll
      for (int kc = 0; kc < 2; ++kc){
        const half8 fv = *reinterpret_cast<const half8*>(
            vb + (dt*16 + lr)*128 + ((kc*64 + lc*16) ^ swz));
        acc[dt] = MFMA16(kc ? pa1 : pa0, fv, acc[dt]);
      }
    }

    __syncthreads();   // drains next-tile gloads; guards buffer swap
    cur ^= 1;
  }

  // finalize: ghost term = 2^(truemax - m); denom broadcast per q-row
  const float den = l + exp2_fast(tm - m);
  float rden[4];
#pragma unroll
  for (int r = 0; r < 4; ++r)
    rden[r] = __shfl(den, (lc << 4) | (lc*4 + r), 64);
#pragma unroll
  for (int dt = 0; dt < 4; ++dt)
#pragma unroll
    for (int r = 0; r < 4; ++r){
      const float o = acc[dt][r] / rden[r];
      const int q = q0 + wid*16 + lc*4 + r;
      const int d = dt*16 + lr;
      Ao[((size_t)(b*S_LEN + q)) * E_DIM + hh*D_DIM + d] = (_Float16)o;
    }
}

// ---------------- launch ----------------
extern "C" void kernel_launch(void* const* d_in, const int* in_sizes, int n_in,
                              void* d_out, int out_size, void* d_ws, size_t ws_size,
                              hipStream_t stream){
  const float* X    = (const float*)d_in[0];
  const float* Wqkv = (const float*)d_in[1];
  const float* Wo   = (const float*)d_in[2];
  float* out = (float*)d_out;

  _Float16* w = (_Float16*)d_ws;
  size_t off = 0;
  auto alloc = [&](size_t n){ _Float16* p = w + off; off += n; return p; };
  const size_t ME   = (size_t)M_ROWS * E_DIM;
  const size_t WQ   = (size_t)N3 * E_DIM;
  const size_t WOsz = (size_t)E_DIM * E_DIM;
  const size_t QK   = (size_t)NBH * S_LEN * D_DIM;
  _Float16 *Xh = alloc(ME);
  _Float16 *Wqh = alloc(WQ);
  _Float16 *Woh = alloc(WOsz);
  _Float16 *Qh = alloc(QK), *Kh = alloc(QK), *Vth = alloc(QK);
  _Float16 *Ahalf = alloc(ME);

  cast_x_kernel<<<(int)(ME/4/256), 256, 0, stream>>>(X, Xh, (int)(ME/4));
  transpose_half<<<dim3(N3/32, E_DIM/32), 256, 0, stream>>>(Wqkv, Wqh, E_DIM, N3);
  transpose_half<<<dim3(E_DIM/32, E_DIM/32), 256, 0, stream>>>(Wo, Woh, E_DIM, E_DIM);

  gemm97<1><<<dim3(N3/128, M_ROWS/128), 256, 0, stream>>>(
      Xh, Wqh, E_DIM, N3, nullptr, Qh, Kh, Vth);

  attn_kernel<<<dim3(32, NBH), 256, 0, stream>>>(Qh, Kh, Vth, Ahalf);

  gemm97<0><<<dim3(E_DIM/128, M_ROWS/128), 256, 0, stream>>>(
      Ahalf, Woh, E_DIM, E_DIM, out, nullptr, nullptr, nullptr);
}

// Round 9
// 123.369 us; speedup vs baseline: 3.1230x; 1.0208x over previous
//
#include <hip/hip_runtime.h>

typedef float    f32x4  __attribute__((ext_vector_type(4)));
typedef _Float16 half8  __attribute__((ext_vector_type(8)));
typedef _Float16 half4v __attribute__((ext_vector_type(4)));

#define MFMA16(a,b,c) __builtin_amdgcn_mfma_f32_16x16x32_f16(a,b,c,0,0,0)

__device__ __forceinline__ float exp2_fast(float x){
  float y; asm("v_exp_f32 %0, %1" : "=v"(y) : "v"(x)); return y;
}
// async global->LDS, 16B per lane; LDS dest is wave-uniform base + lane*16
__device__ __forceinline__ void gload_lds16(const _Float16* g, _Float16* l){
  __builtin_amdgcn_global_load_lds(
      (const __attribute__((address_space(1))) unsigned int*)(g),
      (__attribute__((address_space(3))) unsigned int*)(l),
      16, 0, 0);
}

#define S_LEN 2048
#define E_DIM 1024
#define H_NUM 16
#define D_DIM 64
#define NBH   32
#define M_ROWS 4096
#define N3    3072
#define LOG2E 1.44269504089f

// ---------------- prep: fp32 -> fp16 cast ----------------
__global__ void cast_x_kernel(const float* __restrict__ in,
                              _Float16* __restrict__ hi, int n4){
  int i = blockIdx.x * 256 + threadIdx.x;
  if (i >= n4) return;
  const float4 v = reinterpret_cast<const float4*>(in)[i];
  half4v h;
  h[0] = (_Float16)v.x; h[1] = (_Float16)v.y;
  h[2] = (_Float16)v.z; h[3] = (_Float16)v.w;
  *reinterpret_cast<half4v*>(&hi[i*4]) = h;
}

// out[n][k] = in[k][n], single fp16. in is R x C, out is C x R.
__global__ void transpose_half(const float* __restrict__ in,
                               _Float16* __restrict__ hi, int R, int C){
  __shared__ float tile[32][33];
  int bx = blockIdx.x * 32, by = blockIdx.y * 32;
  int tx = threadIdx.x & 31, ty = threadIdx.x >> 5;   // 256 threads = 32x8
#pragma unroll
  for (int i = ty; i < 32; i += 8)
    tile[i][tx] = in[(size_t)(by + i) * C + bx + tx];
  __syncthreads();
#pragma unroll
  for (int i = ty; i < 32; i += 8)
    hi[(size_t)(bx + i) * R + by + tx] = (_Float16)tile[tx][i];
}

// ---------------- fp16 GEMM (m97 structure + T2 swizzle) --------------------
// C = A @ B^T(rowmajor N x K). 128x128 tile, BK=64, 4 waves, global_load_lds
// staging; LDS dest linear, global source col inverse-XOR-swizzled, reads
// XOR-swizzled (rule #21) -> b128 reads at the 8-lane/quad structural floor.
template<int EPI>
__global__ __launch_bounds__(256, 3) void gemm97(
    const _Float16* __restrict__ A, const _Float16* __restrict__ B,
    int Kdim, int Ndim, float* __restrict__ Cout,
    _Float16* __restrict__ qh, _Float16* __restrict__ kh, _Float16* __restrict__ vh)
{
  __shared__ __align__(16) _Float16 sA[128][64], sB[128][64];
  const int tid = threadIdx.x;
  const int m0 = blockIdx.y * 128, n0 = blockIdx.x * 128;
  const int wid = tid >> 6, lane = tid & 63;
  const int wr = (wid >> 1) * 64, wc = (wid & 1) * 64;
  const int lr = lane & 15, lc = lane >> 4;
  const int ldrow = lane >> 3;                        // 0..7 within chunk
  const int ldcol = ((lane & 7) ^ ldrow) * 8;         // inverse-swizzled source col
  const int swz = (lr & 7) << 4;                      // byte XOR for reads

  f32x4 acc[4][4] = {};
  const int nK = Kdim >> 6;
  for (int ks = 0; ks < nK; ++ks){
    const int k0 = ks << 6;
#pragma unroll
    for (int cc = 0; cc < 4; ++cc){
      const int c = wid * 4 + cc;
      const int row = c * 8 + ldrow;
      gload_lds16(&A[(size_t)(m0 + row) * Kdim + k0 + ldcol], &sA[c*8][0]);
      gload_lds16(&B[(size_t)(n0 + row) * Kdim + k0 + ldcol], &sB[c*8][0]);
    }
    __syncthreads();
    const char* ab = (const char*)&sA[0][0];
    const char* bb = (const char*)&sB[0][0];
#pragma unroll
    for (int kk = 0; kk < 64; kk += 32){
      half8 fa[4], fb[4];
#pragma unroll
      for (int t = 0; t < 4; ++t){
        fa[t] = *reinterpret_cast<const half8*>(
            ab + (wr + t*16 + lr)*128 + ((kk*2 + lc*16) ^ swz));
        fb[t] = *reinterpret_cast<const half8*>(
            bb + (wc + t*16 + lr)*128 + ((kk*2 + lc*16) ^ swz));
      }
#pragma unroll
      for (int mt = 0; mt < 4; ++mt)
#pragma unroll
        for (int nt = 0; nt < 4; ++nt)
          acc[mt][nt] = MFMA16(fa[mt], fb[nt], acc[mt][nt]);
    }
    __syncthreads();
  }
#pragma unroll
  for (int mt = 0; mt < 4; ++mt)
#pragma unroll
    for (int nt = 0; nt < 4; ++nt)
#pragma unroll
      for (int r = 0; r < 4; ++r){
        const int m = m0 + wr + mt*16 + lc*4 + r;
        const int n = n0 + wc + nt*16 + lr;
        float v = acc[mt][nt][r];
        if (EPI == 0){
          Cout[(size_t)m * Ndim + n] = v;
        } else {
          const int t = n >> 10, rem = n & 1023, hh = rem >> 6, d = rem & 63;
          const int b = m >> 11, s = m & 2047;
          const int bh = b * H_NUM + hh;
          if (t == 0) v *= (0.125f * LOG2E);  // fold 1/sqrt(64) and log2(e) into Q
          size_t o;
          if (t == 2)  o = ((size_t)bh * D_DIM + d) * S_LEN + s;   // V transposed
          else         o = ((size_t)bh * S_LEN + s) * D_DIM + d;
          _Float16* ph = (t == 0) ? qh : (t == 1) ? kh : vh;
          ph[o] = (_Float16)v;
        }
      }
}

// ---------------- flash attention, transposed-QK in-register softmax ----------
// Grid 32x32, one q-tile per block, 3 blocks/CU. XCD-aware remap: each XCD
// serves bh in {xcd, xcd+8, xcd+16, xcd+24} (2MB K/V -> L2-resident), qt
// descending so heavy blocks dispatch first.
__global__ __launch_bounds__(256, 3) void attn_kernel(
    const _Float16* __restrict__ Qh, const _Float16* __restrict__ Kh,
    const _Float16* __restrict__ Vth, _Float16* __restrict__ Ao)
{
  __shared__ __align__(16) _Float16 sK[2][64][64], sV[2][64][64];
  __shared__ __align__(16) _Float16 sP[4][16][72];   // per-wave P [q][k], pad 72
  const int tid = threadIdx.x, wid = tid >> 6, lane = tid & 63;
  const int id  = blockIdx.x + 32 * blockIdx.y;
  const int xcd = id & 7, seq = id >> 3;
  const int bh  = xcd + 8 * (seq & 3);
  const int qt  = 31 - (seq >> 2);
  const int q0 = qt * 64;
  const int nT = qt + 1;
  const int lr = lane & 15, lc = lane >> 4;
  const int swz = (lr & 7) << 4;        // byte XOR for swizzled fragment reads
  const size_t base = (size_t)bh * S_LEN * D_DIM;

  // staging geometry: wave w stages chunks {2w,2w+1} (8 rows each) of K and V
  const int lrow = lane >> 3;                       // 0..7
  const int cswz = ((lane & 7) ^ lrow) * 8;         // inverse-swizzled source col (halfs)

  auto stage = [&](int t, int b){
    const int kv0 = t * 64;
#pragma unroll
    for (int cc = 0; cc < 2; ++cc){
      const int c = wid * 2 + cc;
      const int row = c * 8 + lrow;
      gload_lds16(&Kh[base + (size_t)(kv0 + row) * D_DIM + cswz], &sK[b][c*8][0]);
      gload_lds16(&Vth[base + (size_t)row * S_LEN + kv0 + cswz], &sV[b][c*8][0]);
    }
  };

  const int b = bh >> 4, hh = bh & 15;

  // Q fragments (B-operand), hoisted; Q already scaled by log2e/8
  half8 fq[2];
  {
    const int qrow = q0 + wid*16 + lr;
#pragma unroll
    for (int kc = 0; kc < 2; ++kc)
      fq[kc] = *reinterpret_cast<const half8*>(&Qh[base + (size_t)qrow * 64 + kc*32 + lc*8]);
  }

  f32x4 acc[4] = {};
  float m = -1e30f, l = 0.f, tm = -1e30f;   // per-lane stats for q = lr

  stage(0, 0);
  __syncthreads();

  int cur = 0;
  for (int t = 0; t < nT; ++t){
    if (t + 1 < nT) stage(t + 1, cur ^ 1);   // async loads hide under compute

    // ST = K·Q^T: lane holds q=lr (col), k = nt*16 + lc*4 + r (row)
    const char* kb = (const char*)&sK[cur][0][0];
    f32x4 sc[4];
#pragma unroll
    for (int nt = 0; nt < 4; ++nt){
      f32x4 z = {};
#pragma unroll
      for (int kc = 0; kc < 2; ++kc){
        const half8 fk = *reinterpret_cast<const half8*>(
            kb + (nt*16 + lr)*128 + ((kc*64 + lc*16) ^ swz));
        z = MFMA16(fk, fq[kc], z);
      }
      sc[nt] = z;
    }

    if (t == qt){   // diagonal: mask k > q
#pragma unroll
      for (int nt = 0; nt < 4; ++nt)
#pragma unroll
        for (int r = 0; r < 4; ++r)
          if (nt*16 + lc*4 + r > wid*16 + lr) sc[nt][r] = -1e30f;
    }

    // in-lane max over 16 + 2 cross-lane hops (lanes lr, lr+16, lr+32, lr+48)
    f32x4 a;
#pragma unroll
    for (int j = 0; j < 4; ++j)
      a[j] = fmaxf(fmaxf(sc[0][j], sc[1][j]), fmaxf(sc[2][j], sc[3][j]));
    float mx = fmaxf(fmaxf(a[0], a[1]), fmaxf(a[2], a[3]));
    mx = fmaxf(mx, __shfl_xor(mx, 16));
    mx = fmaxf(mx, __shfl_xor(mx, 32));
    tm = fmaxf(tm, mx);

    if (__any(mx > m + 8.0f)){   // defer-max THR=8 (log2 units)
      const float mn = fmaxf(m, mx);
      const float s = exp2_fast(m - mn);
      l *= s; m = mn;
      float rs[4];
#pragma unroll
      for (int r = 0; r < 4; ++r)
        rs[r] = __shfl(s, (lc << 4) | (lc*4 + r), 64);
#pragma unroll
      for (int dt = 0; dt < 4; ++dt)
#pragma unroll
        for (int r = 0; r < 4; ++r) acc[dt][r] *= rs[r];
    }

    // P = exp2(sc - m); in-lane sum + 2 hops
    f32x4 ssum = {};
#pragma unroll
    for (int nt = 0; nt < 4; ++nt){
#pragma unroll
      for (int r = 0; r < 4; ++r) sc[nt][r] = exp2_fast(sc[nt][r] - m);
      ssum += sc[nt];
    }
    float s1 = (ssum[0] + ssum[1]) + (ssum[2] + ssum[3]);
    s1 += __shfl_xor(s1, 16);
    s1 += __shfl_xor(s1, 32);
    l += s1;

    // pack P pairs -> 4 x ds_write_b64 of consecutive k (k = 16nt + 4lc + 0..3)
#pragma unroll
    for (int nt = 0; nt < 4; ++nt){
      int2 pk;
      pk.x = __builtin_bit_cast(int, __builtin_amdgcn_cvt_pkrtz(sc[nt][0], sc[nt][1]));
      pk.y = __builtin_bit_cast(int, __builtin_amdgcn_cvt_pkrtz(sc[nt][2], sc[nt][3]));
      *reinterpret_cast<int2*>(&sP[wid][lr][nt*16 + lc*4]) = pk;
    }

    // PV: pa is the A-fragment (row q=lr, k = kc*32 + lc*8 + j)
    const half8 pa0 = *reinterpret_cast<const half8*>(&sP[wid][lr][lc*8]);
    const half8 pa1 = *reinterpret_cast<const half8*>(&sP[wid][lr][32 + lc*8]);
    const char* vb = (const char*)&sV[cur][0][0];
#pragma unroll
    for (int dt = 0; dt < 4; ++dt){
#pragma unroll
      for (int kc = 0; kc < 2; ++kc){
        const half8 fv = *reinterpret_cast<const half8*>(
            vb + (dt*16 + lr)*128 + ((kc*64 + lc*16) ^ swz));
        acc[dt] = MFMA16(kc ? pa1 : pa0, fv, acc[dt]);
      }
    }

    __syncthreads();   // drains next-tile gloads; guards buffer swap
    cur ^= 1;
  }

  // finalize: ghost term = 2^(truemax - m); denom broadcast per q-row
  const float den = l + exp2_fast(tm - m);
  float rden[4];
#pragma unroll
  for (int r = 0; r < 4; ++r)
    rden[r] = __shfl(den, (lc << 4) | (lc*4 + r), 64);
#pragma unroll
  for (int dt = 0; dt < 4; ++dt)
#pragma unroll
    for (int r = 0; r < 4; ++r){
      const float o = acc[dt][r] / rden[r];
      const int q = q0 + wid*16 + lc*4 + r;
      const int d = dt*16 + lr;
      Ao[((size_t)(b*S_LEN + q)) * E_DIM + hh*D_DIM + d] = (_Float16)o;
    }
}

// ---------------- launch ----------------
extern "C" void kernel_launch(void* const* d_in, const int* in_sizes, int n_in,
                              void* d_out, int out_size, void* d_ws, size_t ws_size,
                              hipStream_t stream){
  const float* X    = (const float*)d_in[0];
  const float* Wqkv = (const float*)d_in[1];
  const float* Wo   = (const float*)d_in[2];
  float* out = (float*)d_out;

  _Float16* w = (_Float16*)d_ws;
  size_t off = 0;
  auto alloc = [&](size_t n){ _Float16* p = w + off; off += n; return p; };
  const size_t ME   = (size_t)M_ROWS * E_DIM;
  const size_t WQ   = (size_t)N3 * E_DIM;
  const size_t WOsz = (size_t)E_DIM * E_DIM;
  const size_t QK   = (size_t)NBH * S_LEN * D_DIM;
  _Float16 *Xh = alloc(ME);
  _Float16 *Wqh = alloc(WQ);
  _Float16 *Woh = alloc(WOsz);
  _Float16 *Qh = alloc(QK), *Kh = alloc(QK), *Vth = alloc(QK);
  _Float16 *Ahalf = alloc(ME);

  cast_x_kernel<<<(int)(ME/4/256), 256, 0, stream>>>(X, Xh, (int)(ME/4));
  transpose_half<<<dim3(N3/32, E_DIM/32), 256, 0, stream>>>(Wqkv, Wqh, E_DIM, N3);
  transpose_half<<<dim3(E_DIM/32, E_DIM/32), 256, 0, stream>>>(Wo, Woh, E_DIM, E_DIM);

  gemm97<1><<<dim3(N3/128, M_ROWS/128), 256, 0, stream>>>(
      Xh, Wqh, E_DIM, N3, nullptr, Qh, Kh, Vth);

  attn_kernel<<<dim3(32, NBH), 256, 0, stream>>>(Qh, Kh, Vth, Ahalf);

  gemm97<0><<<dim3(E_DIM/128, M_ROWS/128), 256, 0, stream>>>(
      Ahalf, Woh, E_DIM, E_DIM, out, nullptr, nullptr, nullptr);
}